// Round 12
// baseline (245.110 us; speedup 1.0000x reference)
//
#include <hip/hip_runtime.h>

#define NN 16512      // N = K + EXER nodes
#define KK 128        // feature dim
#define K3 384        // 3 graphs concatenated along K
#define EE 262144     // edges per graph
#define BB 2048       // batch
#define HH 64         // history length
#define NKf ((size_t)NN * KK)
#define NB 64         // hist blocks per graph
#define EPB (EE / NB) // 4096 edges per block
#define NP (NN / 2)   // 8256 packed u16-pair counters
#define RPB 16        // rows per k_layer block
#define CAP 512       // staged edges per graph per block (mean ~254)

typedef unsigned int u32;
typedef unsigned short u16;
typedef short bf16x8 __attribute__((ext_vector_type(8)));
typedef float f32x4 __attribute__((ext_vector_type(4)));

__device__ __forceinline__ float sgm(float x) { return 1.0f / (1.0f + __expf(-x)); }

__device__ __forceinline__ u16 f2bf(float f) {          // round-to-nearest-even
  u32 u = __float_as_uint(f);
  u32 r = u + 0x7fffu + ((u >> 16) & 1u);
  return (u16)(r >> 16);
}
__device__ __forceinline__ float bflo(u32 p) { return __uint_as_float(p << 16); }
__device__ __forceinline__ float bfhi(u32 p) { return __uint_as_float(p & 0xffff0000u); }

// ---------------- graph preprocessing (atomic-free counting sort) ----------------

__global__ __launch_bounds__(256) void k_hist(
    const int* __restrict__ s0, const int* __restrict__ d0,
    const int* __restrict__ s1, const int* __restrict__ d1,
    const int* __restrict__ s2, const int* __restrict__ d2,
    u32* __restrict__ slabO, u32* __restrict__ slabI) {
  int g = blockIdx.y, b = blockIdx.x;
  const int* src = g == 0 ? s0 : (g == 1 ? s1 : s2);
  const int* dst = g == 0 ? d0 : (g == 1 ? d1 : d2);
  __shared__ u32 hO[NP], hI[NP];
  for (int i = threadIdx.x; i < NP; i += 256) { hO[i] = 0; hI[i] = 0; }
  __syncthreads();
  int base = b * EPB;
  for (int i = threadIdx.x; i < EPB; i += 256) {
    int s = src[base + i], d = dst[base + i];
    atomicAdd(&hO[s >> 1], 1u << ((s & 1) * 16));
    atomicAdd(&hI[d >> 1], 1u << ((d & 1) * 16));
  }
  __syncthreads();
  u32* oO = slabO + ((size_t)g * NB + b) * NP;
  u32* oI = slabI + ((size_t)g * NB + b) * NP;
  for (int i = threadIdx.x; i < NP; i += 256) { oO[i] = hO[i]; oI[i] = hI[i]; }
}

__global__ void k_reduce(u32* __restrict__ slabO, u32* __restrict__ slabI,
                         u32* __restrict__ degI, float* __restrict__ rsdO,
                         float* __restrict__ rsdI) {
  int g = blockIdx.y;
  int t = blockIdx.x * 256 + threadIdx.x;
  if (t >= NP) return;
  u32* sO = slabO + (size_t)g * NB * NP + t;
  u32* sI = slabI + (size_t)g * NB * NP + t;
  u32 sumO = 0, pre = 0;
  #pragma unroll 8
  for (int b = 0; b < NB; ++b) sumO += sO[(size_t)b * NP];
  #pragma unroll 8
  for (int b = 0; b < NB; ++b) {
    u32 v = sI[(size_t)b * NP];
    sI[(size_t)b * NP] = pre;          // packed u16 exclusive prefix
    pre += v;
  }
  u32 dOl = sumO & 0xffffu, dOh = sumO >> 16;
  u32 dIl = pre & 0xffffu,  dIh = pre >> 16;
  *(uint2*)(degI + (size_t)g * NN + 2 * t) = make_uint2(dIl, dIh);
  *(float2*)(rsdO + (size_t)g * NN + 2 * t) =
      make_float2(rsqrtf((float)(dOl ? dOl : 1u)), rsqrtf((float)(dOh ? dOh : 1u)));
  *(float2*)(rsdI + (size_t)g * NN + 2 * t) =
      make_float2(rsqrtf((float)(dIl ? dIl : 1u)), rsqrtf((float)(dIh ? dIh : 1u)));
}

__global__ __launch_bounds__(1024) void k_exscan2(const u32* __restrict__ degI,
                                                  u32* __restrict__ rps) {
  int g = blockIdx.x;
  const u32* deg = degI + (size_t)g * NN;
  u32* rp = rps + (size_t)g * (NN + 1);
  int t = threadIdx.x;
  int i0 = t * 17, i1 = i0 + 17 < NN ? i0 + 17 : NN;
  u32 s = 0;
  for (int i = i0; i < i1; ++i) s += deg[i];
  u32 x = s;
  int lane = t & 63, wid = t >> 6;
  #pragma unroll
  for (int off = 1; off < 64; off <<= 1) {
    u32 y = __shfl_up(x, off);
    if (lane >= off) x += y;
  }
  __shared__ u32 wsums[16];
  if (lane == 63) wsums[wid] = x;
  __syncthreads();
  if (t == 0) {
    u32 run = 0;
    #pragma unroll
    for (int i = 0; i < 16; ++i) { u32 tmp = wsums[i]; wsums[i] = run; run += tmp; }
  }
  __syncthreads();
  u32 run = wsums[wid] + x - s;
  for (int i = i0; i < i1; ++i) { rp[i] = run; run += deg[i]; }
  if (t == 0) rp[NN] = EE;
}

// edata[idx] = { src, norm(f32) } -> single 8B store per edge
__global__ __launch_bounds__(256) void k_scatter2(
    const int* __restrict__ s0, const int* __restrict__ d0,
    const int* __restrict__ s1, const int* __restrict__ d1,
    const int* __restrict__ s2, const int* __restrict__ d2,
    const u32* __restrict__ slabI, const u32* __restrict__ rps,
    const float* __restrict__ rsdO, const float* __restrict__ rsdI,
    uint2* __restrict__ edatas) {
  int g = blockIdx.y, b = blockIdx.x;
  const int* src = g == 0 ? s0 : (g == 1 ? s1 : s2);
  const int* dst = g == 0 ? d0 : (g == 1 ? d1 : d2);
  const u32* rp = rps + (size_t)g * (NN + 1);
  const u32* pre = slabI + ((size_t)g * NB + b) * NP;
  const float* rO = rsdO + (size_t)g * NN;
  const float* rI = rsdI + (size_t)g * NN;
  uint2* ed = edatas + (size_t)g * EE;
  __shared__ u32 cur[NN];
  for (int i = threadIdx.x; i < NP; i += 256) {
    u32 p = pre[i];
    cur[2 * i]     = rp[2 * i] + (p & 0xffffu);
    cur[2 * i + 1] = rp[2 * i + 1] + (p >> 16);
  }
  __syncthreads();
  int base = b * EPB;
  for (int i = threadIdx.x; i < EPB; i += 256) {
    int s = src[base + i], d = dst[base + i];
    u32 idx = atomicAdd(&cur[d], 1u);
    ed[idx] = make_uint2((u32)s, __float_as_uint(rO[s] * rI[d]));
  }
}

// ---------------- fused prep: entity->bf16 | W pre-swizzle | bias sums ----------------
// Bsw[((l*96 + nb*12 + ks)*64 + lane)*8 + j] = bf16( W[l, g, kin, kout] )
//   k = ks*32 + (lane>>4)*8 + j ; g = k>>7 ; kin = k&127 ; kout = nb*16 + (lane&15)

__global__ void k_prep(const float* __restrict__ entity, u16* __restrict__ xent,
                       const float* __restrict__ W, u16* __restrict__ Bsw,
                       const float* __restrict__ b, float* __restrict__ bsum) {
  int bid = blockIdx.x;
  if (bid < 1032) {                       // cvt: NN*KK/8 = 264192 items
    int t = bid * 256 + threadIdx.x;
    if (t >= NN * KK / 8) return;
    const float4* p = (const float4*)entity + (size_t)t * 2;
    float4 v0 = p[0], v1 = p[1];
    bf16x8 o;
    o[0] = (short)f2bf(v0.x); o[1] = (short)f2bf(v0.y);
    o[2] = (short)f2bf(v0.z); o[3] = (short)f2bf(v0.w);
    o[4] = (short)f2bf(v1.x); o[5] = (short)f2bf(v1.y);
    o[6] = (short)f2bf(v1.z); o[7] = (short)f2bf(v1.w);
    *(bf16x8*)(xent + (size_t)t * 8) = o;
  } else if (bid < 1104) {                // prepB: 18432 items
    int t = (bid - 1032) * 256 + threadIdx.x;
    if (t >= 3 * 8 * 12 * 64) return;
    int lane = t & 63;
    int ks = (t >> 6) % 12;
    int nb = ((t >> 6) / 12) % 8;
    int l  = (t >> 6) / 96;
    int kout = nb * 16 + (lane & 15);
    int kb = ks * 32 + (lane >> 4) * 8;
    bf16x8 v;
    #pragma unroll
    for (int j = 0; j < 8; ++j) {
      int k = kb + j; int g = k >> 7; int kin = k & 127;
      v[j] = (short)f2bf(W[(((size_t)l * 3 + g) * KK + kin) * KK + kout]);
    }
    *(bf16x8*)(Bsw + (size_t)t * 8) = v;
  } else {                                // bias sums: 384 items
    int t = (bid - 1104) * 256 + threadIdx.x;
    if (t >= 3 * KK) return;
    int l = t >> 7, c = t & 127;
    bsum[l * KK + c] = b[(l * 3 + 0) * KK + c] + b[(l * 3 + 1) * KK + c] + b[(l * 3 + 2) * KK + c];
  }
}

// ---------------- fused layer: SpMM (3 graphs -> LDS) + MFMA GEMM + epilogue ----------
// Block owns 16 rows; 8 waves; 48 row-tasks (single-row, stride 8). Per row: 4-deep
// rolling software pipeline over edge quads; masked clamp-loads make ALL rows run the
// deep pipeline (4 gathers in flight). Edge meta staged in LDS (global fallback).
// mode: 1 = Sx = entity + v ; else Sx += v
//       2 = Ss = v ; 4 = Ssb = bf16(Ss + v) ; 8 = skip h write

#define ACC8(A, P, N)                                              \
  A[0] += bflo(P.x) * N; A[1] += bfhi(P.x) * N;                    \
  A[2] += bflo(P.y) * N; A[3] += bfhi(P.y) * N;                    \
  A[4] += bflo(P.z) * N; A[5] += bfhi(P.z) * N;                    \
  A[6] += bflo(P.w) * N; A[7] += bfhi(P.w) * N;

// masked quad load into stage S: clamp index, zero norm for out-of-range lanes
#define LOADQ(S, E) {                                              \
    u32 ii = (E) + slot;                                           \
    u32 cc = ii < cnt ? ii : cnt - 1;                              \
    uint2 mm = mp[cc];                                             \
    n##S = ii < cnt ? __uint_as_float(mm.y) : 0.f;                 \
    p##S = *(const uint4*)(x + (size_t)mm.x * KK + cg * 8); }

__global__ __launch_bounds__(512) void k_layer(
    const u16* __restrict__ x, const u32* __restrict__ rps,
    const uint2* __restrict__ edatas, const u16* __restrict__ Bsw,
    const float* __restrict__ bsum, u16* __restrict__ hout,
    const float* __restrict__ entity, float* __restrict__ Sx,
    float* __restrict__ Ss, u16* __restrict__ Ssb, int mode)
{
  __shared__ u16 At[RPB][392];            // 12.25 KB; row stride 784B -> 2-way (free)
  __shared__ uint2 meta[3][CAP];          // 12 KB staged edge metadata
  __shared__ u32 rpl[3][RPB + 1];         // row pointers
  const int tid = threadIdx.x;
  const int wv = tid >> 6, lane = tid & 63;
  const int m0 = blockIdx.x * RPB;
  const int slot = lane >> 4, cg = lane & 15;

  if (tid < 3 * (RPB + 1))
    rpl[tid / (RPB + 1)][tid % (RPB + 1)] =
        rps[(size_t)(tid / (RPB + 1)) * (NN + 1) + m0 + tid % (RPB + 1)];
  __syncthreads();

  // ---- stage edge metadata (contiguous CSR slices) ----
  #pragma unroll
  for (int g = 0; g < 3; ++g) {
    u32 b0 = rpl[g][0];
    u32 cnt = rpl[g][RPB] - b0; if (cnt > CAP) cnt = CAP;
    const uint2* ed = edatas + (size_t)g * EE + b0;
    for (u32 i = tid; i < cnt; i += 512) meta[g][i] = ed[i];
  }
  __syncthreads();

  // ---- SpMM phase: 48 row-tasks, 4-deep rolling pipeline per row ----
  for (int t = wv; t < 48; t += 8) {
    int g = t >> 4, r = t & 15;
    u32 beg = rpl[g][r], cnt = rpl[g][r + 1] - beg;
    const uint2* mp = (rpl[g][RPB] - rpl[g][0] <= CAP)
                          ? &meta[g][beg - rpl[g][0]]
                          : edatas + (size_t)g * EE + beg;
    float acc[8] = {0.f, 0.f, 0.f, 0.f, 0.f, 0.f, 0.f, 0.f};
    if (cnt) {
      float n0, n1, n2, n3;
      uint4 p0, p1, p2, p3;
      LOADQ(0, 0u) LOADQ(1, 4u) LOADQ(2, 8u) LOADQ(3, 12u)
      u32 elim = ((cnt + 3u) & ~3u);      // nq*4
      for (u32 e = 16; e < elim; e += 16) {
        ACC8(acc, p0, n0) LOADQ(0, e)
        ACC8(acc, p1, n1) LOADQ(1, e + 4)
        ACC8(acc, p2, n2) LOADQ(2, e + 8)
        ACC8(acc, p3, n3) LOADQ(3, e + 12)
      }
      ACC8(acc, p0, n0) ACC8(acc, p1, n1)
      ACC8(acc, p2, n2) ACC8(acc, p3, n3)
    }
    #pragma unroll
    for (int i = 0; i < 8; ++i) {
      acc[i] += __shfl_xor(acc[i], 16);
      acc[i] += __shfl_xor(acc[i], 32);
    }
    if (slot == 0) {
      u32 o0 = ((u32)f2bf(acc[1]) << 16) | (u32)f2bf(acc[0]);
      u32 o1 = ((u32)f2bf(acc[3]) << 16) | (u32)f2bf(acc[2]);
      u32 o2 = ((u32)f2bf(acc[5]) << 16) | (u32)f2bf(acc[4]);
      u32 o3 = ((u32)f2bf(acc[7]) << 16) | (u32)f2bf(acc[6]);
      *(uint4*)(&At[r][g * KK + cg * 8]) = make_uint4(o0, o1, o2, o3);
    }
  }
  __syncthreads();

  // ---- MFMA phase: 16x128 = At(16x384) @ B(384x128); wave wv -> cols wv*16.. ----
  const int lr = lane & 15, lk = lane >> 4;
  f32x4 acc2 = {0.f, 0.f, 0.f, 0.f};
  const u16* aB = Bsw + (size_t)wv * 6144 + (size_t)lane * 8;
  #pragma unroll
  for (int ks = 0; ks < 12; ++ks) {
    bf16x8 a = *(const bf16x8*)(&At[lr][ks * 32 + lk * 8]);
    bf16x8 b = *(const bf16x8*)(aB + ks * 512);
    acc2 = __builtin_amdgcn_mfma_f32_16x16x32_bf16(a, b, acc2, 0, 0, 0);
  }

  int col = wv * 16 + lr;
  float bv = bsum[col];
  int rowb = m0 + lk * 4;
  #pragma unroll
  for (int r = 0; r < 4; ++r) {
    size_t idx = (size_t)(rowb + r) * KK + col;
    float v = acc2[r] + bv;
    if (!(mode & 8)) hout[idx] = f2bf(v);
    float sx = (mode & 1) ? (entity[idx] + v) : (Sx[idx] + v);
    Sx[idx] = sx;
    if (mode & 2) Ss[idx] = v;
    else if (mode & 4) Ssb[idx] = f2bf(Ss[idx] + v);
  }
}

// ---------------- concept projections (tiny) ----------------

__global__ __launch_bounds__(256) void k_cproj(
    const float* __restrict__ Sx, const float* __restrict__ Wstu,
    const float* __restrict__ Wexer, float* __restrict__ cstu,
    float* __restrict__ cexer)
{
  int wv = threadIdx.x >> 6, lane = threadIdx.x & 63;
  int w = blockIdx.x * 4 + wv;            // 32 blocks -> 128 rows
  float2 c = *(const float2*)(Sx + (size_t)w * KK + lane * 2);
  c.x *= 0.25f; c.y *= 0.25f;
  float2 ws = *(const float2*)(Wstu + KK + lane * 2);
  float2 we = *(const float2*)(Wexer + KK + lane * 2);
  float ps = c.x * ws.x + c.y * ws.y;
  float pe = c.x * we.x + c.y * we.y;
  #pragma unroll
  for (int off = 32; off; off >>= 1) { ps += __shfl_xor(ps, off); pe += __shfl_xor(pe, off); }
  if (lane == 0) { cstu[w] = ps; cexer[w] = pe; }
}

// ---------------- final: history mean + projections + head, one wave per item ----------

__global__ __launch_bounds__(256) void k_final(
    const u16* __restrict__ Ssb, const int* __restrict__ hist, const int* __restrict__ hlen,
    const float* __restrict__ Sx, const float* __restrict__ cstu,
    const float* __restrict__ cexer, const float* __restrict__ Wstu,
    const float* __restrict__ Wexer, const float* __restrict__ W3,
    const float* __restrict__ disc, const int* __restrict__ exid,
    const float* __restrict__ kn, const float* __restrict__ bstu,
    const float* __restrict__ bexer, const float* __restrict__ b3,
    float* __restrict__ out)
{
  int wv = threadIdx.x >> 6, lane = threadIdx.x & 63;
  int w = blockIdx.x * 4 + wv;            // 512 blocks -> 2048 items
  int slot = lane >> 4, cg = lane & 15;   // quad-row history gather layout
  int len = hlen[w];
  const int* hrow = hist + w * HH;
  float acc[8] = {0.f, 0.f, 0.f, 0.f, 0.f, 0.f, 0.f, 0.f};
  int h = 0;
  for (; h + 4 <= len; h += 4) {
    int id = hrow[h + slot];
    uint4 p = *(const uint4*)(Ssb + (size_t)(KK + id) * KK + cg * 8);
    acc[0] += bflo(p.x); acc[1] += bfhi(p.x);
    acc[2] += bflo(p.y); acc[3] += bfhi(p.y);
    acc[4] += bflo(p.z); acc[5] += bfhi(p.z);
    acc[6] += bflo(p.w); acc[7] += bfhi(p.w);
  }
  if (h + slot < len) {
    int id = hrow[h + slot];
    uint4 p = *(const uint4*)(Ssb + (size_t)(KK + id) * KK + cg * 8);
    acc[0] += bflo(p.x); acc[1] += bfhi(p.x);
    acc[2] += bflo(p.y); acc[3] += bfhi(p.y);
    acc[4] += bflo(p.z); acc[5] += bfhi(p.z);
    acc[6] += bflo(p.w); acc[7] += bfhi(p.w);
  }
  #pragma unroll
  for (int i = 0; i < 8; ++i) {           // all lanes get full row sums
    acc[i] += __shfl_xor(acc[i], 16);
    acc[i] += __shfl_xor(acc[i], 32);
  }
  float sc = 0.5f / (float)len;

  int eid = exid[w];
  const int c0 = cg * 8;                  // this lane's 8 columns
  const float* sxr = Sx + (size_t)(KK + eid) * KK + c0;
  float ps = 0.f, pe = 0.f;
  float se[8];
  #pragma unroll
  for (int j = 0; j < 8; ++j) {
    se[j] = 0.25f * sxr[j];               // exer_emb
    ps += (acc[j] * sc) * Wstu[c0 + j];
    pe += se[j] * Wexer[c0 + j];
  }
  #pragma unroll
  for (int off = 8; off; off >>= 1) {     // reduce over the 16-lane col group
    ps += __shfl_xor(ps, off);
    pe += __shfl_xor(pe, off);
  }
  float s_stu = ps + bstu[0];
  float s_exer = pe + bexer[0];
  float ed = 10.f * sgm(disc[eid]);

  float px = 0.f;
  #pragma unroll
  for (int j = 0; j < 8; ++j) {
    int c = c0 + j;
    float xv = ed * (sgm(s_stu + cstu[c]) - sgm(s_exer + cexer[c])) * kn[(size_t)w * KK + c];
    px += xv * W3[c];
  }
  #pragma unroll
  for (int off = 8; off; off >>= 1) px += __shfl_xor(px, off);
  if (lane == 0) out[w] = sgm(px + b3[0]);
}

// ---------------- host ----------------

extern "C" void kernel_launch(void* const* d_in, const int* in_sizes, int n_in,
                              void* d_out, int out_size, void* d_ws, size_t ws_size,
                              hipStream_t stream)
{
  const float* entity = (const float*)d_in[0];
  const float* gcnW   = (const float*)d_in[1];
  const float* gcnB   = (const float*)d_in[2];
  const float* disc   = (const float*)d_in[3];
  const float* Wstu   = (const float*)d_in[4];
  const float* bstu   = (const float*)d_in[5];
  const float* Wexer  = (const float*)d_in[6];
  const float* bexer  = (const float*)d_in[7];
  const float* W3     = (const float*)d_in[8];
  const float* b3     = (const float*)d_in[9];
  const float* kn     = (const float*)d_in[10];
  const int* exer_id  = (const int*)d_in[12];
  const int* history  = (const int*)d_in[14];
  const int* hlen     = (const int*)d_in[15];
  const int* s0 = (const int*)d_in[16], *dd0 = (const int*)d_in[17];
  const int* s1 = (const int*)d_in[18], *dd1 = (const int*)d_in[19];
  const int* s2 = (const int*)d_in[20], *dd2 = (const int*)d_in[21];

  char* ws = (char*)d_ws;
  size_t off = 0;
  auto take = [&](size_t bytes) -> char* {
    char* p = ws + off;
    off = (off + bytes + 255) & ~(size_t)255;
    return p;
  };
  u16*   xent  = (u16*)take(NKf * 2);
  u16*   hA    = (u16*)take(NKf * 2);
  u16*   hB    = (u16*)take(NKf * 2);
  float* Sx    = (float*)take(NKf * 4);
  float* Ss    = (float*)take(NKf * 4);
  u16*   Ssb   = (u16*)take(NKf * 2);
  float* cstu  = (float*)take(KK * 4);
  float* cexer = (float*)take(KK * 4);
  u16*   Bsw   = (u16*)take((size_t)3 * 49152 * 2);
  float* bsum  = (float*)take((size_t)3 * KK * 4);
  u32*   degI  = (u32*)take((size_t)3 * NN * 4);
  float* rsdO  = (float*)take((size_t)3 * NN * 4);
  float* rsdI  = (float*)take((size_t)3 * NN * 4);
  u32*   rp    = (u32*)take((size_t)3 * (NN + 1) * 4);
  uint2* edata = (uint2*)take((size_t)3 * EE * 8);
  u32*   slabO = (u32*)take((size_t)3 * NB * NP * 4);
  u32*   slabI = (u32*)take((size_t)3 * NB * NP * 4);
  (void)ws_size; (void)in_sizes; (void)n_in; (void)out_size;

  k_hist<<<dim3(NB, 3), 256, 0, stream>>>(s0, dd0, s1, dd1, s2, dd2, slabO, slabI);
  k_reduce<<<dim3((NP + 255) / 256, 3), 256, 0, stream>>>(slabO, slabI, degI, rsdO, rsdI);
  k_exscan2<<<3, 1024, 0, stream>>>(degI, rp);
  k_scatter2<<<dim3(NB, 3), 256, 0, stream>>>(s0, dd0, s1, dd1, s2, dd2, slabI, rp,
                                              rsdO, rsdI, edata);
  k_prep<<<1106, 256, 0, stream>>>(entity, xent, gcnW, Bsw, gcnB, bsum);

  const u16* xs[3] = {xent, hA, hB};
  u16* outs[3]     = {hA, hB, hA};
  const int modes[3] = {1, 2, 4 | 8};
  for (int l = 0; l < 3; ++l)
    k_layer<<<NN / RPB, 512, 0, stream>>>(xs[l], rp, edata, Bsw + (size_t)l * 49152,
                                          bsum + (size_t)l * KK, outs[l], entity,
                                          Sx, Ss, Ssb, modes[l]);

  k_cproj<<<32, 256, 0, stream>>>(Sx, Wstu, Wexer, cstu, cexer);
  k_final<<<BB / 4, 256, 0, stream>>>(Ssb, history, hlen, Sx, cstu, cexer, Wstu, Wexer,
                                      W3, disc, exer_id, kn, bstu, bexer, b3,
                                      (float*)d_out);
}

// Round 13
// 206.723 us; speedup vs baseline: 1.1857x; 1.1857x over previous
//
#include <hip/hip_runtime.h>

#define NN 16512      // N = K + EXER nodes
#define KK 128        // feature dim
#define K3 384        // 3 graphs concatenated along K
#define EE 262144     // edges per graph
#define BB 2048       // batch
#define HH 64         // history length
#define NKf ((size_t)NN * KK)
#define NB 64         // hist blocks per graph
#define EPB (EE / NB) // 4096 edges per block
#define NP (NN / 2)   // 8256 packed u16-pair counters
#define RPB 8         // rows per k_layer block
#define CAP 256       // staged edges per graph per block (mean ~127)

typedef unsigned int u32;
typedef unsigned short u16;
typedef short bf16x8 __attribute__((ext_vector_type(8)));
typedef float f32x4 __attribute__((ext_vector_type(4)));

__device__ __forceinline__ float sgm(float x) { return 1.0f / (1.0f + __expf(-x)); }

__device__ __forceinline__ u16 f2bf(float f) {          // round-to-nearest-even
  u32 u = __float_as_uint(f);
  u32 r = u + 0x7fffu + ((u >> 16) & 1u);
  return (u16)(r >> 16);
}
__device__ __forceinline__ float bflo(u32 p) { return __uint_as_float(p << 16); }
__device__ __forceinline__ float bfhi(u32 p) { return __uint_as_float(p & 0xffff0000u); }

// ---------------- graph preprocessing (atomic-free counting sort) ----------------

__global__ __launch_bounds__(256) void k_hist(
    const int* __restrict__ s0, const int* __restrict__ d0,
    const int* __restrict__ s1, const int* __restrict__ d1,
    const int* __restrict__ s2, const int* __restrict__ d2,
    u32* __restrict__ slabO, u32* __restrict__ slabI) {
  int g = blockIdx.y, b = blockIdx.x;
  const int* src = g == 0 ? s0 : (g == 1 ? s1 : s2);
  const int* dst = g == 0 ? d0 : (g == 1 ? d1 : d2);
  __shared__ u32 hO[NP], hI[NP];
  for (int i = threadIdx.x; i < NP; i += 256) { hO[i] = 0; hI[i] = 0; }
  __syncthreads();
  int base = b * EPB;
  for (int i = threadIdx.x; i < EPB; i += 256) {
    int s = src[base + i], d = dst[base + i];
    atomicAdd(&hO[s >> 1], 1u << ((s & 1) * 16));
    atomicAdd(&hI[d >> 1], 1u << ((d & 1) * 16));
  }
  __syncthreads();
  u32* oO = slabO + ((size_t)g * NB + b) * NP;
  u32* oI = slabI + ((size_t)g * NB + b) * NP;
  for (int i = threadIdx.x; i < NP; i += 256) { oO[i] = hO[i]; oI[i] = hI[i]; }
}

__global__ void k_reduce(u32* __restrict__ slabO, u32* __restrict__ slabI,
                         u32* __restrict__ degI, float* __restrict__ rsdO,
                         float* __restrict__ rsdI) {
  int g = blockIdx.y;
  int t = blockIdx.x * 256 + threadIdx.x;
  if (t >= NP) return;
  u32* sO = slabO + (size_t)g * NB * NP + t;
  u32* sI = slabI + (size_t)g * NB * NP + t;
  u32 sumO = 0, pre = 0;
  #pragma unroll 8
  for (int b = 0; b < NB; ++b) sumO += sO[(size_t)b * NP];
  #pragma unroll 8
  for (int b = 0; b < NB; ++b) {
    u32 v = sI[(size_t)b * NP];
    sI[(size_t)b * NP] = pre;          // packed u16 exclusive prefix
    pre += v;
  }
  u32 dOl = sumO & 0xffffu, dOh = sumO >> 16;
  u32 dIl = pre & 0xffffu,  dIh = pre >> 16;
  *(uint2*)(degI + (size_t)g * NN + 2 * t) = make_uint2(dIl, dIh);
  *(float2*)(rsdO + (size_t)g * NN + 2 * t) =
      make_float2(rsqrtf((float)(dOl ? dOl : 1u)), rsqrtf((float)(dOh ? dOh : 1u)));
  *(float2*)(rsdI + (size_t)g * NN + 2 * t) =
      make_float2(rsqrtf((float)(dIl ? dIl : 1u)), rsqrtf((float)(dIh ? dIh : 1u)));
}

__global__ __launch_bounds__(1024) void k_exscan2(const u32* __restrict__ degI,
                                                  u32* __restrict__ rps) {
  int g = blockIdx.x;
  const u32* deg = degI + (size_t)g * NN;
  u32* rp = rps + (size_t)g * (NN + 1);
  int t = threadIdx.x;
  int i0 = t * 17, i1 = i0 + 17 < NN ? i0 + 17 : NN;
  u32 s = 0;
  for (int i = i0; i < i1; ++i) s += deg[i];
  u32 x = s;
  int lane = t & 63, wid = t >> 6;
  #pragma unroll
  for (int off = 1; off < 64; off <<= 1) {
    u32 y = __shfl_up(x, off);
    if (lane >= off) x += y;
  }
  __shared__ u32 wsums[16];
  if (lane == 63) wsums[wid] = x;
  __syncthreads();
  if (t == 0) {
    u32 run = 0;
    #pragma unroll
    for (int i = 0; i < 16; ++i) { u32 tmp = wsums[i]; wsums[i] = run; run += tmp; }
  }
  __syncthreads();
  u32 run = wsums[wid] + x - s;
  for (int i = i0; i < i1; ++i) { rp[i] = run; run += deg[i]; }
  if (t == 0) rp[NN] = EE;
}

// edata[idx] = { src, norm(f32) } -> single 8B store per edge
__global__ __launch_bounds__(256) void k_scatter2(
    const int* __restrict__ s0, const int* __restrict__ d0,
    const int* __restrict__ s1, const int* __restrict__ d1,
    const int* __restrict__ s2, const int* __restrict__ d2,
    const u32* __restrict__ slabI, const u32* __restrict__ rps,
    const float* __restrict__ rsdO, const float* __restrict__ rsdI,
    uint2* __restrict__ edatas) {
  int g = blockIdx.y, b = blockIdx.x;
  const int* src = g == 0 ? s0 : (g == 1 ? s1 : s2);
  const int* dst = g == 0 ? d0 : (g == 1 ? d1 : d2);
  const u32* rp = rps + (size_t)g * (NN + 1);
  const u32* pre = slabI + ((size_t)g * NB + b) * NP;
  const float* rO = rsdO + (size_t)g * NN;
  const float* rI = rsdI + (size_t)g * NN;
  uint2* ed = edatas + (size_t)g * EE;
  __shared__ u32 cur[NN];
  for (int i = threadIdx.x; i < NP; i += 256) {
    u32 p = pre[i];
    cur[2 * i]     = rp[2 * i] + (p & 0xffffu);
    cur[2 * i + 1] = rp[2 * i + 1] + (p >> 16);
  }
  __syncthreads();
  int base = b * EPB;
  for (int i = threadIdx.x; i < EPB; i += 256) {
    int s = src[base + i], d = dst[base + i];
    u32 idx = atomicAdd(&cur[d], 1u);
    ed[idx] = make_uint2((u32)s, __float_as_uint(rO[s] * rI[d]));
  }
}

// ---------------- fused prep: entity->bf16 | W pre-swizzle | bias sums ----------------
// Bsw[((l*96 + nb*12 + ks)*64 + lane)*8 + j] = bf16( W[l, g, kin, kout] )
//   k = ks*32 + (lane>>4)*8 + j ; g = k>>7 ; kin = k&127 ; kout = nb*16 + (lane&15)

__global__ void k_prep(const float* __restrict__ entity, u16* __restrict__ xent,
                       const float* __restrict__ W, u16* __restrict__ Bsw,
                       const float* __restrict__ b, float* __restrict__ bsum) {
  int bid = blockIdx.x;
  if (bid < 1032) {                       // cvt: NN*KK/8 = 264192 items
    int t = bid * 256 + threadIdx.x;
    if (t >= NN * KK / 8) return;
    const float4* p = (const float4*)entity + (size_t)t * 2;
    float4 v0 = p[0], v1 = p[1];
    bf16x8 o;
    o[0] = (short)f2bf(v0.x); o[1] = (short)f2bf(v0.y);
    o[2] = (short)f2bf(v0.z); o[3] = (short)f2bf(v0.w);
    o[4] = (short)f2bf(v1.x); o[5] = (short)f2bf(v1.y);
    o[6] = (short)f2bf(v1.z); o[7] = (short)f2bf(v1.w);
    *(bf16x8*)(xent + (size_t)t * 8) = o;
  } else if (bid < 1104) {                // prepB: 18432 items
    int t = (bid - 1032) * 256 + threadIdx.x;
    if (t >= 3 * 8 * 12 * 64) return;
    int lane = t & 63;
    int ks = (t >> 6) % 12;
    int nb = ((t >> 6) / 12) % 8;
    int l  = (t >> 6) / 96;
    int kout = nb * 16 + (lane & 15);
    int kb = ks * 32 + (lane >> 4) * 8;
    bf16x8 v;
    #pragma unroll
    for (int j = 0; j < 8; ++j) {
      int k = kb + j; int g = k >> 7; int kin = k & 127;
      v[j] = (short)f2bf(W[(((size_t)l * 3 + g) * KK + kin) * KK + kout]);
    }
    *(bf16x8*)(Bsw + (size_t)t * 8) = v;
  } else {                                // bias sums: 384 items
    int t = (bid - 1104) * 256 + threadIdx.x;
    if (t >= 3 * KK) return;
    int l = t >> 7, c = t & 127;
    bsum[l * KK + c] = b[(l * 3 + 0) * KK + c] + b[(l * 3 + 1) * KK + c] + b[(l * 3 + 2) * KK + c];
  }
}

// ---------------- fused layer: SpMM (3 graphs -> LDS) + MFMA GEMM + epilogue ----------
// 256 threads / 4 waves; block owns 8 rows; 24 row-tasks (6/wave), lean r7-style
// single-chain quad gather; meta staged in LDS; grid 2064 = ~8 blocks/CU (fine
// granularity: less round-quantization tail + better imbalance packing).
// At zero-padded to 16 rows for the MFMA shape.
// mode: 1 = Sx = entity + v ; else Sx += v
//       2 = Ss = v ; 4 = Ssb = bf16(Ss + v) ; 8 = skip h write

#define ACC8(A, P, N)                                              \
  A[0] += bflo(P.x) * N; A[1] += bfhi(P.x) * N;                    \
  A[2] += bflo(P.y) * N; A[3] += bfhi(P.y) * N;                    \
  A[4] += bflo(P.z) * N; A[5] += bfhi(P.z) * N;                    \
  A[6] += bflo(P.w) * N; A[7] += bfhi(P.w) * N;

__global__ __launch_bounds__(256) void k_layer(
    const u16* __restrict__ x, const u32* __restrict__ rps,
    const uint2* __restrict__ edatas, const u16* __restrict__ Bsw,
    const float* __restrict__ bsum, u16* __restrict__ hout,
    const float* __restrict__ entity, float* __restrict__ Sx,
    float* __restrict__ Ss, u16* __restrict__ Ssb, int mode)
{
  __shared__ u16 At[16][392];             // 12.25 KB; rows 8-15 stay zero (MFMA pad)
  __shared__ uint2 meta[3][CAP];          // 6 KB staged edge metadata
  __shared__ u32 rpl[3][RPB + 1];         // row pointers
  const int tid = threadIdx.x;
  const int wv = tid >> 6, lane = tid & 63;
  const int m0 = blockIdx.x * RPB;
  const int slot = lane >> 4, cg = lane & 15;

  if (tid < 3 * (RPB + 1))
    rpl[tid / (RPB + 1)][tid % (RPB + 1)] =
        rps[(size_t)(tid / (RPB + 1)) * (NN + 1) + m0 + tid % (RPB + 1)];
  // zero the padding rows 8..15 (8*392 u16 = 1568 u32)
  {
    u32* zp = (u32*)&At[8][0];
    for (int i = tid; i < 8 * 392 / 2; i += 256) zp[i] = 0;
  }
  __syncthreads();

  // ---- stage edge metadata (contiguous CSR slices) ----
  #pragma unroll
  for (int g = 0; g < 3; ++g) {
    u32 b0 = rpl[g][0];
    u32 cnt = rpl[g][RPB] - b0; if (cnt > CAP) cnt = CAP;
    const uint2* ed = edatas + (size_t)g * EE + b0;
    for (u32 i = tid; i < cnt; i += 256) meta[g][i] = ed[i];
  }
  __syncthreads();

  // ---- SpMM phase: 24 row-tasks, 6 per wave ----
  for (int t = wv; t < 24; t += 4) {
    int g = t >> 3, r = t & 7;
    u32 beg = rpl[g][r], cnt = rpl[g][r + 1] - beg;
    const uint2* mp = (rpl[g][RPB] - rpl[g][0] <= CAP)
                          ? &meta[g][beg - rpl[g][0]]
                          : edatas + (size_t)g * EE + beg;
    float acc[8] = {0.f, 0.f, 0.f, 0.f, 0.f, 0.f, 0.f, 0.f};
    u32 e = 0;
    for (; e + 4 <= cnt; e += 4) {
      uint2 m = mp[e + slot];
      float n = __uint_as_float(m.y);
      uint4 p = *(const uint4*)(x + (size_t)m.x * KK + cg * 8);
      ACC8(acc, p, n)
    }
    if (e + slot < cnt) {
      uint2 m = mp[e + slot];
      float n = __uint_as_float(m.y);
      uint4 p = *(const uint4*)(x + (size_t)m.x * KK + cg * 8);
      ACC8(acc, p, n)
    }
    #pragma unroll
    for (int i = 0; i < 8; ++i) {
      acc[i] += __shfl_xor(acc[i], 16);
      acc[i] += __shfl_xor(acc[i], 32);
    }
    if (slot == 0) {
      u32 o0 = ((u32)f2bf(acc[1]) << 16) | (u32)f2bf(acc[0]);
      u32 o1 = ((u32)f2bf(acc[3]) << 16) | (u32)f2bf(acc[2]);
      u32 o2 = ((u32)f2bf(acc[5]) << 16) | (u32)f2bf(acc[4]);
      u32 o3 = ((u32)f2bf(acc[7]) << 16) | (u32)f2bf(acc[6]);
      *(uint4*)(&At[r][g * KK + cg * 8]) = make_uint4(o0, o1, o2, o3);
    }
  }
  __syncthreads();

  // ---- MFMA phase: (8+8pad)x128 = At @ B(384x128); wave wv -> cols wv*32..+31 ----
  const int lr = lane & 15, lk = lane >> 4;
  f32x4 z = {0.f, 0.f, 0.f, 0.f};
  f32x4 acc2[2] = {z, z};
  const u16* aB = Bsw + (size_t)(wv * 2) * 6144 + (size_t)lane * 8;
  #pragma unroll
  for (int ks = 0; ks < 12; ++ks) {
    bf16x8 a  = *(const bf16x8*)(&At[lr][ks * 32 + lk * 8]);
    bf16x8 b0 = *(const bf16x8*)(aB + ks * 512);
    bf16x8 b1 = *(const bf16x8*)(aB + 6144 + ks * 512);
    acc2[0] = __builtin_amdgcn_mfma_f32_16x16x32_bf16(a, b0, acc2[0], 0, 0, 0);
    acc2[1] = __builtin_amdgcn_mfma_f32_16x16x32_bf16(a, b1, acc2[1], 0, 0, 0);
  }

  if (lk < 2) {                           // rows m0 .. m0+7 only (rest is pad)
    #pragma unroll
    for (int j = 0; j < 2; ++j) {
      int col = wv * 32 + j * 16 + lr;
      float bv = bsum[col];
      int rowb = m0 + lk * 4;
      #pragma unroll
      for (int r = 0; r < 4; ++r) {
        size_t idx = (size_t)(rowb + r) * KK + col;
        float v = acc2[j][r] + bv;
        if (!(mode & 8)) hout[idx] = f2bf(v);
        float sx = (mode & 1) ? (entity[idx] + v) : (Sx[idx] + v);
        Sx[idx] = sx;
        if (mode & 2) Ss[idx] = v;
        else if (mode & 4) Ssb[idx] = f2bf(Ss[idx] + v);
      }
    }
  }
}

// ---------------- concept projections (tiny) ----------------

__global__ __launch_bounds__(256) void k_cproj(
    const float* __restrict__ Sx, const float* __restrict__ Wstu,
    const float* __restrict__ Wexer, float* __restrict__ cstu,
    float* __restrict__ cexer)
{
  int wv = threadIdx.x >> 6, lane = threadIdx.x & 63;
  int w = blockIdx.x * 4 + wv;            // 32 blocks -> 128 rows
  float2 c = *(const float2*)(Sx + (size_t)w * KK + lane * 2);
  c.x *= 0.25f; c.y *= 0.25f;
  float2 ws = *(const float2*)(Wstu + KK + lane * 2);
  float2 we = *(const float2*)(Wexer + KK + lane * 2);
  float ps = c.x * ws.x + c.y * ws.y;
  float pe = c.x * we.x + c.y * we.y;
  #pragma unroll
  for (int off = 32; off; off >>= 1) { ps += __shfl_xor(ps, off); pe += __shfl_xor(pe, off); }
  if (lane == 0) { cstu[w] = ps; cexer[w] = pe; }
}

// ---------------- final: history mean + projections + head, one wave per item ----------

__global__ __launch_bounds__(256) void k_final(
    const u16* __restrict__ Ssb, const int* __restrict__ hist, const int* __restrict__ hlen,
    const float* __restrict__ Sx, const float* __restrict__ cstu,
    const float* __restrict__ cexer, const float* __restrict__ Wstu,
    const float* __restrict__ Wexer, const float* __restrict__ W3,
    const float* __restrict__ disc, const int* __restrict__ exid,
    const float* __restrict__ kn, const float* __restrict__ bstu,
    const float* __restrict__ bexer, const float* __restrict__ b3,
    float* __restrict__ out)
{
  int wv = threadIdx.x >> 6, lane = threadIdx.x & 63;
  int w = blockIdx.x * 4 + wv;            // 512 blocks -> 2048 items
  int slot = lane >> 4, cg = lane & 15;   // quad-row history gather layout
  int len = hlen[w];
  const int* hrow = hist + w * HH;
  float acc[8] = {0.f, 0.f, 0.f, 0.f, 0.f, 0.f, 0.f, 0.f};
  int h = 0;
  for (; h + 4 <= len; h += 4) {
    int id = hrow[h + slot];
    uint4 p = *(const uint4*)(Ssb + (size_t)(KK + id) * KK + cg * 8);
    acc[0] += bflo(p.x); acc[1] += bfhi(p.x);
    acc[2] += bflo(p.y); acc[3] += bfhi(p.y);
    acc[4] += bflo(p.z); acc[5] += bfhi(p.z);
    acc[6] += bflo(p.w); acc[7] += bfhi(p.w);
  }
  if (h + slot < len) {
    int id = hrow[h + slot];
    uint4 p = *(const uint4*)(Ssb + (size_t)(KK + id) * KK + cg * 8);
    acc[0] += bflo(p.x); acc[1] += bfhi(p.x);
    acc[2] += bflo(p.y); acc[3] += bfhi(p.y);
    acc[4] += bflo(p.z); acc[5] += bfhi(p.z);
    acc[6] += bflo(p.w); acc[7] += bfhi(p.w);
  }
  #pragma unroll
  for (int i = 0; i < 8; ++i) {           // all lanes get full row sums
    acc[i] += __shfl_xor(acc[i], 16);
    acc[i] += __shfl_xor(acc[i], 32);
  }
  float sc = 0.5f / (float)len;

  int eid = exid[w];
  const int c0 = cg * 8;                  // this lane's 8 columns
  const float* sxr = Sx + (size_t)(KK + eid) * KK + c0;
  float ps = 0.f, pe = 0.f;
  float se[8];
  #pragma unroll
  for (int j = 0; j < 8; ++j) {
    se[j] = 0.25f * sxr[j];               // exer_emb
    ps += (acc[j] * sc) * Wstu[c0 + j];
    pe += se[j] * Wexer[c0 + j];
  }
  #pragma unroll
  for (int off = 8; off; off >>= 1) {     // reduce over the 16-lane col group
    ps += __shfl_xor(ps, off);
    pe += __shfl_xor(pe, off);
  }
  float s_stu = ps + bstu[0];
  float s_exer = pe + bexer[0];
  float ed = 10.f * sgm(disc[eid]);

  float px = 0.f;
  #pragma unroll
  for (int j = 0; j < 8; ++j) {
    int c = c0 + j;
    float xv = ed * (sgm(s_stu + cstu[c]) - sgm(s_exer + cexer[c])) * kn[(size_t)w * KK + c];
    px += xv * W3[c];
  }
  #pragma unroll
  for (int off = 8; off; off >>= 1) px += __shfl_xor(px, off);
  if (lane == 0) out[w] = sgm(px + b3[0]);
}

// ---------------- host ----------------

extern "C" void kernel_launch(void* const* d_in, const int* in_sizes, int n_in,
                              void* d_out, int out_size, void* d_ws, size_t ws_size,
                              hipStream_t stream)
{
  const float* entity = (const float*)d_in[0];
  const float* gcnW   = (const float*)d_in[1];
  const float* gcnB   = (const float*)d_in[2];
  const float* disc   = (const float*)d_in[3];
  const float* Wstu   = (const float*)d_in[4];
  const float* bstu   = (const float*)d_in[5];
  const float* Wexer  = (const float*)d_in[6];
  const float* bexer  = (const float*)d_in[7];
  const float* W3     = (const float*)d_in[8];
  const float* b3     = (const float*)d_in[9];
  const float* kn     = (const float*)d_in[10];
  const int* exer_id  = (const int*)d_in[12];
  const int* history  = (const int*)d_in[14];
  const int* hlen     = (const int*)d_in[15];
  const int* s0 = (const int*)d_in[16], *dd0 = (const int*)d_in[17];
  const int* s1 = (const int*)d_in[18], *dd1 = (const int*)d_in[19];
  const int* s2 = (const int*)d_in[20], *dd2 = (const int*)d_in[21];

  char* ws = (char*)d_ws;
  size_t off = 0;
  auto take = [&](size_t bytes) -> char* {
    char* p = ws + off;
    off = (off + bytes + 255) & ~(size_t)255;
    return p;
  };
  u16*   xent  = (u16*)take(NKf * 2);
  u16*   hA    = (u16*)take(NKf * 2);
  u16*   hB    = (u16*)take(NKf * 2);
  float* Sx    = (float*)take(NKf * 4);
  float* Ss    = (float*)take(NKf * 4);
  u16*   Ssb   = (u16*)take(NKf * 2);
  float* cstu  = (float*)take(KK * 4);
  float* cexer = (float*)take(KK * 4);
  u16*   Bsw   = (u16*)take((size_t)3 * 49152 * 2);
  float* bsum  = (float*)take((size_t)3 * KK * 4);
  u32*   degI  = (u32*)take((size_t)3 * NN * 4);
  float* rsdO  = (float*)take((size_t)3 * NN * 4);
  float* rsdI  = (float*)take((size_t)3 * NN * 4);
  u32*   rp    = (u32*)take((size_t)3 * (NN + 1) * 4);
  uint2* edata = (uint2*)take((size_t)3 * EE * 8);
  u32*   slabO = (u32*)take((size_t)3 * NB * NP * 4);
  u32*   slabI = (u32*)take((size_t)3 * NB * NP * 4);
  (void)ws_size; (void)in_sizes; (void)n_in; (void)out_size;

  k_hist<<<dim3(NB, 3), 256, 0, stream>>>(s0, dd0, s1, dd1, s2, dd2, slabO, slabI);
  k_reduce<<<dim3((NP + 255) / 256, 3), 256, 0, stream>>>(slabO, slabI, degI, rsdO, rsdI);
  k_exscan2<<<3, 1024, 0, stream>>>(degI, rp);
  k_scatter2<<<dim3(NB, 3), 256, 0, stream>>>(s0, dd0, s1, dd1, s2, dd2, slabI, rp,
                                              rsdO, rsdI, edata);
  k_prep<<<1106, 256, 0, stream>>>(entity, xent, gcnW, Bsw, gcnB, bsum);

  const u16* xs[3] = {xent, hA, hB};
  u16* outs[3]     = {hA, hB, hA};
  const int modes[3] = {1, 2, 4 | 8};
  for (int l = 0; l < 3; ++l)
    k_layer<<<NN / RPB, 256, 0, stream>>>(xs[l], rp, edata, Bsw + (size_t)l * 49152,
                                          bsum + (size_t)l * KK, outs[l], entity,
                                          Sx, Ss, Ssb, modes[l]);

  k_cproj<<<32, 256, 0, stream>>>(Sx, Wstu, Wexer, cstu, cexer);
  k_final<<<BB / 4, 256, 0, stream>>>(Ssb, history, hlen, Sx, cstu, cexer, Wstu, Wexer,
                                      W3, disc, exer_id, kn, bstu, bexer, b3,
                                      (float*)d_out);
}

// Round 14
// 178.401 us; speedup vs baseline: 1.3739x; 1.1588x over previous
//
#include <hip/hip_runtime.h>

#define NN 16512      // N = K + EXER nodes
#define KK 128        // feature dim
#define K3 384        // 3 graphs concatenated along K
#define EE 262144     // edges per graph
#define BB 2048       // batch
#define HH 64         // history length
#define NKf ((size_t)NN * KK)
#define NB 64         // hist blocks per graph
#define EPB (EE / NB) // 4096 edges per block
#define NP (NN / 2)   // 8256 packed u16-pair counters
#define RPB 16        // rows per k_layer block
#define CAP 512       // staged edges per graph per block (mean ~254)

typedef unsigned int u32;
typedef unsigned short u16;
typedef short bf16x8 __attribute__((ext_vector_type(8)));
typedef float f32x4 __attribute__((ext_vector_type(4)));

__device__ __forceinline__ float sgm(float x) { return 1.0f / (1.0f + __expf(-x)); }

__device__ __forceinline__ u16 f2bf(float f) {          // round-to-nearest-even
  u32 u = __float_as_uint(f);
  u32 r = u + 0x7fffu + ((u >> 16) & 1u);
  return (u16)(r >> 16);
}
__device__ __forceinline__ float bflo(u32 p) { return __uint_as_float(p << 16); }
__device__ __forceinline__ float bfhi(u32 p) { return __uint_as_float(p & 0xffff0000u); }

// ---------------- graph preprocessing (atomic-free counting sort) ----------------

__global__ __launch_bounds__(256) void k_hist(
    const int* __restrict__ s0, const int* __restrict__ d0,
    const int* __restrict__ s1, const int* __restrict__ d1,
    const int* __restrict__ s2, const int* __restrict__ d2,
    u32* __restrict__ slabO, u32* __restrict__ slabI) {
  int g = blockIdx.y, b = blockIdx.x;
  const int* src = g == 0 ? s0 : (g == 1 ? s1 : s2);
  const int* dst = g == 0 ? d0 : (g == 1 ? d1 : d2);
  __shared__ u32 hO[NP], hI[NP];
  for (int i = threadIdx.x; i < NP; i += 256) { hO[i] = 0; hI[i] = 0; }
  __syncthreads();
  int base = b * EPB;
  for (int i = threadIdx.x; i < EPB; i += 256) {
    int s = src[base + i], d = dst[base + i];
    atomicAdd(&hO[s >> 1], 1u << ((s & 1) * 16));
    atomicAdd(&hI[d >> 1], 1u << ((d & 1) * 16));
  }
  __syncthreads();
  u32* oO = slabO + ((size_t)g * NB + b) * NP;
  u32* oI = slabI + ((size_t)g * NB + b) * NP;
  for (int i = threadIdx.x; i < NP; i += 256) { oO[i] = hO[i]; oI[i] = hI[i]; }
}

__global__ void k_reduce(u32* __restrict__ slabO, u32* __restrict__ slabI,
                         u32* __restrict__ degI, float* __restrict__ rsdO,
                         float* __restrict__ rsdI) {
  int g = blockIdx.y;
  int t = blockIdx.x * 256 + threadIdx.x;
  if (t >= NP) return;
  u32* sO = slabO + (size_t)g * NB * NP + t;
  u32* sI = slabI + (size_t)g * NB * NP + t;
  u32 sumO = 0, pre = 0;
  #pragma unroll 8
  for (int b = 0; b < NB; ++b) sumO += sO[(size_t)b * NP];
  #pragma unroll 8
  for (int b = 0; b < NB; ++b) {
    u32 v = sI[(size_t)b * NP];
    sI[(size_t)b * NP] = pre;          // packed u16 exclusive prefix
    pre += v;
  }
  u32 dOl = sumO & 0xffffu, dOh = sumO >> 16;
  u32 dIl = pre & 0xffffu,  dIh = pre >> 16;
  *(uint2*)(degI + (size_t)g * NN + 2 * t) = make_uint2(dIl, dIh);
  *(float2*)(rsdO + (size_t)g * NN + 2 * t) =
      make_float2(rsqrtf((float)(dOl ? dOl : 1u)), rsqrtf((float)(dOh ? dOh : 1u)));
  *(float2*)(rsdI + (size_t)g * NN + 2 * t) =
      make_float2(rsqrtf((float)(dIl ? dIl : 1u)), rsqrtf((float)(dIh ? dIh : 1u)));
}

__global__ __launch_bounds__(1024) void k_exscan2(const u32* __restrict__ degI,
                                                  u32* __restrict__ rps) {
  int g = blockIdx.x;
  const u32* deg = degI + (size_t)g * NN;
  u32* rp = rps + (size_t)g * (NN + 1);
  int t = threadIdx.x;
  int i0 = t * 17, i1 = i0 + 17 < NN ? i0 + 17 : NN;
  u32 s = 0;
  for (int i = i0; i < i1; ++i) s += deg[i];
  u32 x = s;
  int lane = t & 63, wid = t >> 6;
  #pragma unroll
  for (int off = 1; off < 64; off <<= 1) {
    u32 y = __shfl_up(x, off);
    if (lane >= off) x += y;
  }
  __shared__ u32 wsums[16];
  if (lane == 63) wsums[wid] = x;
  __syncthreads();
  if (t == 0) {
    u32 run = 0;
    #pragma unroll
    for (int i = 0; i < 16; ++i) { u32 tmp = wsums[i]; wsums[i] = run; run += tmp; }
  }
  __syncthreads();
  u32 run = wsums[wid] + x - s;
  for (int i = i0; i < i1; ++i) { rp[i] = run; run += deg[i]; }
  if (t == 0) rp[NN] = EE;
}

// edata[idx] = { src, norm(f32) } -> single 8B store per edge
__global__ __launch_bounds__(256) void k_scatter2(
    const int* __restrict__ s0, const int* __restrict__ d0,
    const int* __restrict__ s1, const int* __restrict__ d1,
    const int* __restrict__ s2, const int* __restrict__ d2,
    const u32* __restrict__ slabI, const u32* __restrict__ rps,
    const float* __restrict__ rsdO, const float* __restrict__ rsdI,
    uint2* __restrict__ edatas) {
  int g = blockIdx.y, b = blockIdx.x;
  const int* src = g == 0 ? s0 : (g == 1 ? s1 : s2);
  const int* dst = g == 0 ? d0 : (g == 1 ? d1 : d2);
  const u32* rp = rps + (size_t)g * (NN + 1);
  const u32* pre = slabI + ((size_t)g * NB + b) * NP;
  const float* rO = rsdO + (size_t)g * NN;
  const float* rI = rsdI + (size_t)g * NN;
  uint2* ed = edatas + (size_t)g * EE;
  __shared__ u32 cur[NN];
  for (int i = threadIdx.x; i < NP; i += 256) {
    u32 p = pre[i];
    cur[2 * i]     = rp[2 * i] + (p & 0xffffu);
    cur[2 * i + 1] = rp[2 * i + 1] + (p >> 16);
  }
  __syncthreads();
  int base = b * EPB;
  for (int i = threadIdx.x; i < EPB; i += 256) {
    int s = src[base + i], d = dst[base + i];
    u32 idx = atomicAdd(&cur[d], 1u);
    ed[idx] = make_uint2((u32)s, __float_as_uint(rO[s] * rI[d]));
  }
}

// ---------------- fused prep: entity->bf16 | W pre-swizzle | bias sums ----------------
// Bsw[((l*96 + nb*12 + ks)*64 + lane)*8 + j] = bf16( W[l, g, kin, kout] )
//   k = ks*32 + (lane>>4)*8 + j ; g = k>>7 ; kin = k&127 ; kout = nb*16 + (lane&15)

__global__ void k_prep(const float* __restrict__ entity, u16* __restrict__ xent,
                       const float* __restrict__ W, u16* __restrict__ Bsw,
                       const float* __restrict__ b, float* __restrict__ bsum) {
  int bid = blockIdx.x;
  if (bid < 1032) {                       // cvt: NN*KK/8 = 264192 items
    int t = bid * 256 + threadIdx.x;
    if (t >= NN * KK / 8) return;
    const float4* p = (const float4*)entity + (size_t)t * 2;
    float4 v0 = p[0], v1 = p[1];
    bf16x8 o;
    o[0] = (short)f2bf(v0.x); o[1] = (short)f2bf(v0.y);
    o[2] = (short)f2bf(v0.z); o[3] = (short)f2bf(v0.w);
    o[4] = (short)f2bf(v1.x); o[5] = (short)f2bf(v1.y);
    o[6] = (short)f2bf(v1.z); o[7] = (short)f2bf(v1.w);
    *(bf16x8*)(xent + (size_t)t * 8) = o;
  } else if (bid < 1104) {                // prepB: 18432 items
    int t = (bid - 1032) * 256 + threadIdx.x;
    if (t >= 3 * 8 * 12 * 64) return;
    int lane = t & 63;
    int ks = (t >> 6) % 12;
    int nb = ((t >> 6) / 12) % 8;
    int l  = (t >> 6) / 96;
    int kout = nb * 16 + (lane & 15);
    int kb = ks * 32 + (lane >> 4) * 8;
    bf16x8 v;
    #pragma unroll
    for (int j = 0; j < 8; ++j) {
      int k = kb + j; int g = k >> 7; int kin = k & 127;
      v[j] = (short)f2bf(W[(((size_t)l * 3 + g) * KK + kin) * KK + kout]);
    }
    *(bf16x8*)(Bsw + (size_t)t * 8) = v;
  } else {                                // bias sums: 384 items
    int t = (bid - 1104) * 256 + threadIdx.x;
    if (t >= 3 * KK) return;
    int l = t >> 7, c = t & 127;
    bsum[l * KK + c] = b[(l * 3 + 0) * KK + c] + b[(l * 3 + 1) * KK + c] + b[(l * 3 + 2) * KK + c];
  }
}

// ---------------- fused layer: SpMM (3 graphs -> LDS) + MFMA GEMM + epilogue ----------
// r7 structure (best measured): block owns 16 rows; 8 waves; 48 row-tasks; quad-edge
// gather with 4x unroll; meta staged in LDS. NEW: epilogue transposes acc through LDS
// (reusing At as f32 scratch) so all global epilogue traffic is float4/uint2 coalesced.
// mode: 1 = Sx = entity + v ; else Sx += v
//       2 = Ss = v ; 4 = Ssb = bf16(Ss + v) ; 8 = skip h write

#define ACC8(P, N)                                                 \
  acc[0] += bflo(P.x) * N; acc[1] += bfhi(P.x) * N;                \
  acc[2] += bflo(P.y) * N; acc[3] += bfhi(P.y) * N;                \
  acc[4] += bflo(P.z) * N; acc[5] += bfhi(P.z) * N;                \
  acc[6] += bflo(P.w) * N; acc[7] += bfhi(P.w) * N;

#define GATHER_LOOP(MP)                                            \
  for (; e + 16 <= cnt; e += 16) {                                 \
    uint2 ma = MP[e + slot];                                       \
    uint2 mb = MP[e + 4 + slot];                                   \
    uint2 mc = MP[e + 8 + slot];                                   \
    uint2 md = MP[e + 12 + slot];                                  \
    uint4 pa = *(const uint4*)(x + (size_t)ma.x * KK + cg * 8);    \
    uint4 pb = *(const uint4*)(x + (size_t)mb.x * KK + cg * 8);    \
    uint4 pc = *(const uint4*)(x + (size_t)mc.x * KK + cg * 8);    \
    uint4 pd = *(const uint4*)(x + (size_t)md.x * KK + cg * 8);    \
    float na = __uint_as_float(ma.y), nb2 = __uint_as_float(mb.y); \
    float nc = __uint_as_float(mc.y), nd = __uint_as_float(md.y);  \
    ACC8(pa, na) ACC8(pb, nb2) ACC8(pc, nc) ACC8(pd, nd)           \
  }                                                                \
  for (; e + 4 <= cnt; e += 4) {                                   \
    uint2 m = MP[e + slot];                                        \
    float n = __uint_as_float(m.y);                                \
    uint4 p = *(const uint4*)(x + (size_t)m.x * KK + cg * 8);      \
    ACC8(p, n)                                                     \
  }                                                                \
  if (e + slot < cnt) {                                            \
    uint2 m = MP[e + slot];                                        \
    float n = __uint_as_float(m.y);                                \
    uint4 p = *(const uint4*)(x + (size_t)m.x * KK + cg * 8);      \
    ACC8(p, n)                                                     \
  }

__global__ __launch_bounds__(512) void k_layer(
    const u16* __restrict__ x, const u32* __restrict__ rps,
    const uint2* __restrict__ edatas, const u16* __restrict__ Bsw,
    const float* __restrict__ bsum, u16* __restrict__ hout,
    const float* __restrict__ entity, float* __restrict__ Sx,
    float* __restrict__ Ss, u16* __restrict__ Ssb, int mode)
{
  __shared__ u16 At[RPB][392];            // 12.25 KB; also reused as f32 scratch (8 KB)
  __shared__ uint2 meta[3][CAP];          // 12 KB staged edge metadata
  __shared__ u32 rpl[3][RPB + 1];         // row pointers
  const int tid = threadIdx.x;
  const int wv = tid >> 6, lane = tid & 63;
  const int m0 = blockIdx.x * RPB;
  const int slot = lane >> 4, cg = lane & 15;

  if (tid < 3 * (RPB + 1))
    rpl[tid / (RPB + 1)][tid % (RPB + 1)] =
        rps[(size_t)(tid / (RPB + 1)) * (NN + 1) + m0 + tid % (RPB + 1)];
  __syncthreads();

  // ---- stage edge metadata (contiguous CSR slices) ----
  #pragma unroll
  for (int g = 0; g < 3; ++g) {
    u32 b0 = rpl[g][0];
    u32 cnt = rpl[g][RPB] - b0; if (cnt > CAP) cnt = CAP;
    const uint2* ed = edatas + (size_t)g * EE + b0;
    for (u32 i = tid; i < cnt; i += 512) meta[g][i] = ed[i];
  }
  __syncthreads();

  // ---- SpMM phase: 48 row-tasks, quad-edge 4x-unrolled gather ----
  for (int t = wv; t < 48; t += 8) {
    int g = t >> 4, r = t & 15;
    u32 beg = rpl[g][r], cnt = rpl[g][r + 1] - beg;
    float acc[8] = {0.f, 0.f, 0.f, 0.f, 0.f, 0.f, 0.f, 0.f};
    u32 e = 0;
    if (rpl[g][RPB] - rpl[g][0] <= CAP) {
      const uint2* mp = &meta[g][beg - rpl[g][0]];
      GATHER_LOOP(mp)
    } else {                              // overflow fallback (rare)
      const uint2* mp = edatas + (size_t)g * EE + beg;
      GATHER_LOOP(mp)
    }
    #pragma unroll
    for (int i = 0; i < 8; ++i) {
      acc[i] += __shfl_xor(acc[i], 16);
      acc[i] += __shfl_xor(acc[i], 32);
    }
    if (slot == 0) {
      u32 o0 = ((u32)f2bf(acc[1]) << 16) | (u32)f2bf(acc[0]);
      u32 o1 = ((u32)f2bf(acc[3]) << 16) | (u32)f2bf(acc[2]);
      u32 o2 = ((u32)f2bf(acc[5]) << 16) | (u32)f2bf(acc[4]);
      u32 o3 = ((u32)f2bf(acc[7]) << 16) | (u32)f2bf(acc[6]);
      *(uint4*)(&At[r][g * KK + cg * 8]) = make_uint4(o0, o1, o2, o3);
    }
  }
  __syncthreads();

  // ---- MFMA phase: 16x128 = At(16x384) @ B(384x128); wave wv -> cols wv*16.. ----
  const int lr = lane & 15, lk = lane >> 4;
  f32x4 acc2 = {0.f, 0.f, 0.f, 0.f};
  const u16* aB = Bsw + (size_t)wv * 6144 + (size_t)lane * 8;
  #pragma unroll
  for (int ks = 0; ks < 12; ++ks) {
    bf16x8 a = *(const bf16x8*)(&At[lr][ks * 32 + lk * 8]);
    bf16x8 b = *(const bf16x8*)(aB + ks * 512);
    acc2 = __builtin_amdgcn_mfma_f32_16x16x32_bf16(a, b, acc2, 0, 0, 0);
  }
  __syncthreads();                        // all MFMA reads of At done

  // ---- transpose acc through LDS (At reused as 16x128 f32 = 8 KB) ----
  float* Af = (float*)&At[0][0];
  {
    int col = wv * 16 + lr;
    int rowb = lk * 4;
    #pragma unroll
    for (int r = 0; r < 4; ++r) Af[(rowb + r) * KK + col] = acc2[r];
  }
  __syncthreads();

  // ---- vectorized epilogue: thread t -> row t/32, cols (t%32)*4 (float4) ----
  {
    int row = tid >> 5, c4 = (tid & 31) * 4;
    size_t idx = (size_t)(m0 + row) * KK + c4;
    f32x4 v = *(f32x4*)&Af[row * KK + c4];
    f32x4 bv = *(const f32x4*)&bsum[c4];
    v[0] += bv[0]; v[1] += bv[1]; v[2] += bv[2]; v[3] += bv[3];
    if (!(mode & 8)) {
      u32 h0 = ((u32)f2bf(v[1]) << 16) | (u32)f2bf(v[0]);
      u32 h1 = ((u32)f2bf(v[3]) << 16) | (u32)f2bf(v[2]);
      *(uint2*)(hout + idx) = make_uint2(h0, h1);
    }
    f32x4 sx;
    if (mode & 1) {
      f32x4 ev = *(const f32x4*)(entity + idx);
      sx[0] = ev[0] + v[0]; sx[1] = ev[1] + v[1];
      sx[2] = ev[2] + v[2]; sx[3] = ev[3] + v[3];
    } else {
      f32x4 s = *(const f32x4*)(Sx + idx);
      sx[0] = s[0] + v[0]; sx[1] = s[1] + v[1];
      sx[2] = s[2] + v[2]; sx[3] = s[3] + v[3];
    }
    *(f32x4*)(Sx + idx) = sx;
    if (mode & 2) {
      *(f32x4*)(Ss + idx) = v;
    } else if (mode & 4) {
      f32x4 s = *(const f32x4*)(Ss + idx);
      u32 h0 = ((u32)f2bf(s[1] + v[1]) << 16) | (u32)f2bf(s[0] + v[0]);
      u32 h1 = ((u32)f2bf(s[3] + v[3]) << 16) | (u32)f2bf(s[2] + v[2]);
      *(uint2*)(Ssb + idx) = make_uint2(h0, h1);
    }
  }
}

// ---------------- fused post: history mean (quad rows) + concept projections ----------

__global__ __launch_bounds__(256) void k_post(
    const u16* __restrict__ Ssb, const int* __restrict__ hist, const int* __restrict__ hlen,
    float* __restrict__ semb, const float* __restrict__ Sx,
    const float* __restrict__ Wstu, const float* __restrict__ Wexer,
    float* __restrict__ cstu, float* __restrict__ cexer)
{
  int wv = threadIdx.x >> 6, lane = threadIdx.x & 63;
  if (blockIdx.x < 512) {                 // stuemb: 2048 items
    int item = blockIdx.x * 4 + wv;
    int slot = lane >> 4, cg = lane & 15;
    int len = hlen[item];
    const int* hrow = hist + item * HH;
    float acc[8] = {0.f, 0.f, 0.f, 0.f, 0.f, 0.f, 0.f, 0.f};
    int h = 0;
    for (; h + 4 <= len; h += 4) {
      int id = hrow[h + slot];
      uint4 p = *(const uint4*)(Ssb + (size_t)(KK + id) * KK + cg * 8);
      acc[0] += bflo(p.x); acc[1] += bfhi(p.x);
      acc[2] += bflo(p.y); acc[3] += bfhi(p.y);
      acc[4] += bflo(p.z); acc[5] += bfhi(p.z);
      acc[6] += bflo(p.w); acc[7] += bfhi(p.w);
    }
    if (h + slot < len) {
      int id = hrow[h + slot];
      uint4 p = *(const uint4*)(Ssb + (size_t)(KK + id) * KK + cg * 8);
      acc[0] += bflo(p.x); acc[1] += bfhi(p.x);
      acc[2] += bflo(p.y); acc[3] += bfhi(p.y);
      acc[4] += bflo(p.z); acc[5] += bfhi(p.z);
      acc[6] += bflo(p.w); acc[7] += bfhi(p.w);
    }
    #pragma unroll
    for (int i = 0; i < 8; ++i) {
      acc[i] += __shfl_xor(acc[i], 16);
      acc[i] += __shfl_xor(acc[i], 32);
    }
    if (slot == 0) {
      float sc = 0.5f / (float)len;
      float4 o0 = make_float4(acc[0] * sc, acc[1] * sc, acc[2] * sc, acc[3] * sc);
      float4 o1 = make_float4(acc[4] * sc, acc[5] * sc, acc[6] * sc, acc[7] * sc);
      *(float4*)(semb + (size_t)item * KK + cg * 8) = o0;
      *(float4*)(semb + (size_t)item * KK + cg * 8 + 4) = o1;
    }
  } else {                                // cproj: 128 concept rows
    int w = (blockIdx.x - 512) * 4 + wv;
    float2 c = *(const float2*)(Sx + (size_t)w * KK + lane * 2);
    c.x *= 0.25f; c.y *= 0.25f;
    float2 ws = *(const float2*)(Wstu + KK + lane * 2);
    float2 we = *(const float2*)(Wexer + KK + lane * 2);
    float ps = c.x * ws.x + c.y * ws.y;
    float pe = c.x * we.x + c.y * we.y;
    #pragma unroll
    for (int off = 32; off; off >>= 1) { ps += __shfl_xor(ps, off); pe += __shfl_xor(pe, off); }
    if (lane == 0) { cstu[w] = ps; cexer[w] = pe; }
  }
}

__global__ void k_final(const float* __restrict__ Sx, const float* __restrict__ semb,
                        const float* __restrict__ cstu, const float* __restrict__ cexer,
                        const float* __restrict__ Wstu, const float* __restrict__ Wexer,
                        const float* __restrict__ W3, const float* __restrict__ disc,
                        const int* __restrict__ exid, const float* __restrict__ kn,
                        const float* __restrict__ bstu, const float* __restrict__ bexer,
                        const float* __restrict__ b3, float* __restrict__ out) {
  int w = (blockIdx.x * 256 + threadIdx.x) >> 6;   // batch index
  int lane = threadIdx.x & 63;
  if (w >= BB) return;
  int eid = exid[w];
  float2 se = *(const float2*)(Sx + ((size_t)(KK + eid)) * KK + lane * 2);
  se.x *= 0.25f; se.y *= 0.25f;                    // exer_emb
  float2 sm = *(const float2*)(semb + (size_t)w * KK + lane * 2);
  float2 ws = *(const float2*)(Wstu + lane * 2);
  float2 we = *(const float2*)(Wexer + lane * 2);
  float ps = sm.x * ws.x + sm.y * ws.y;
  float pe = se.x * we.x + se.y * we.y;
  #pragma unroll
  for (int off = 32; off; off >>= 1) { ps += __shfl_xor(ps, off); pe += __shfl_xor(pe, off); }
  float s_stu = ps + bstu[0];
  float s_exer = pe + bexer[0];
  float ed = 10.f * sgm(disc[eid]);
  float2 cs = *(const float2*)(cstu + lane * 2);
  float2 ce = *(const float2*)(cexer + lane * 2);
  float2 knv = *(const float2*)(kn + (size_t)w * KK + lane * 2);
  float x0 = ed * (sgm(s_stu + cs.x) - sgm(s_exer + ce.x)) * knv.x;
  float x1 = ed * (sgm(s_stu + cs.y) - sgm(s_exer + ce.y)) * knv.y;
  float2 w3v = *(const float2*)(W3 + lane * 2);
  float px = x0 * w3v.x + x1 * w3v.y;
  #pragma unroll
  for (int off = 32; off; off >>= 1) px += __shfl_xor(px, off);
  if (lane == 0) out[w] = sgm(px + b3[0]);
}

// ---------------- host ----------------

extern "C" void kernel_launch(void* const* d_in, const int* in_sizes, int n_in,
                              void* d_out, int out_size, void* d_ws, size_t ws_size,
                              hipStream_t stream)
{
  const float* entity = (const float*)d_in[0];
  const float* gcnW   = (const float*)d_in[1];
  const float* gcnB   = (const float*)d_in[2];
  const float* disc   = (const float*)d_in[3];
  const float* Wstu   = (const float*)d_in[4];
  const float* bstu   = (const float*)d_in[5];
  const float* Wexer  = (const float*)d_in[6];
  const float* bexer  = (const float*)d_in[7];
  const float* W3     = (const float*)d_in[8];
  const float* b3     = (const float*)d_in[9];
  const float* kn     = (const float*)d_in[10];
  const int* exer_id  = (const int*)d_in[12];
  const int* history  = (const int*)d_in[14];
  const int* hlen     = (const int*)d_in[15];
  const int* s0 = (const int*)d_in[16], *dd0 = (const int*)d_in[17];
  const int* s1 = (const int*)d_in[18], *dd1 = (const int*)d_in[19];
  const int* s2 = (const int*)d_in[20], *dd2 = (const int*)d_in[21];

  char* ws = (char*)d_ws;
  size_t off = 0;
  auto take = [&](size_t bytes) -> char* {
    char* p = ws + off;
    off = (off + bytes + 255) & ~(size_t)255;
    return p;
  };
  u16*   xent  = (u16*)take(NKf * 2);
  u16*   hA    = (u16*)take(NKf * 2);
  u16*   hB    = (u16*)take(NKf * 2);
  float* Sx    = (float*)take(NKf * 4);
  float* Ss    = (float*)take(NKf * 4);
  u16*   Ssb   = (u16*)take(NKf * 2);
  float* semb  = (float*)take((size_t)BB * KK * 4);
  float* cstu  = (float*)take(KK * 4);
  float* cexer = (float*)take(KK * 4);
  u16*   Bsw   = (u16*)take((size_t)3 * 49152 * 2);
  float* bsum  = (float*)take((size_t)3 * KK * 4);
  u32*   degI  = (u32*)take((size_t)3 * NN * 4);
  float* rsdO  = (float*)take((size_t)3 * NN * 4);
  float* rsdI  = (float*)take((size_t)3 * NN * 4);
  u32*   rp    = (u32*)take((size_t)3 * (NN + 1) * 4);
  uint2* edata = (uint2*)take((size_t)3 * EE * 8);
  u32*   slabO = (u32*)take((size_t)3 * NB * NP * 4);
  u32*   slabI = (u32*)take((size_t)3 * NB * NP * 4);
  (void)ws_size; (void)in_sizes; (void)n_in; (void)out_size;

  k_hist<<<dim3(NB, 3), 256, 0, stream>>>(s0, dd0, s1, dd1, s2, dd2, slabO, slabI);
  k_reduce<<<dim3((NP + 255) / 256, 3), 256, 0, stream>>>(slabO, slabI, degI, rsdO, rsdI);
  k_exscan2<<<3, 1024, 0, stream>>>(degI, rp);
  k_scatter2<<<dim3(NB, 3), 256, 0, stream>>>(s0, dd0, s1, dd1, s2, dd2, slabI, rp,
                                              rsdO, rsdI, edata);
  k_prep<<<1106, 256, 0, stream>>>(entity, xent, gcnW, Bsw, gcnB, bsum);

  const u16* xs[3] = {xent, hA, hB};
  u16* outs[3]     = {hA, hB, hA};
  const int modes[3] = {1, 2, 4 | 8};
  for (int l = 0; l < 3; ++l)
    k_layer<<<NN / RPB, 512, 0, stream>>>(xs[l], rp, edata, Bsw + (size_t)l * 49152,
                                          bsum + (size_t)l * KK, outs[l], entity,
                                          Sx, Ss, Ssb, modes[l]);

  k_post<<<544, 256, 0, stream>>>(Ssb, history, hlen, semb, Sx, Wstu, Wexer, cstu, cexer);
  k_final<<<BB * 64 / 256, 256, 0, stream>>>(Sx, semb, cstu, cexer, Wstu, Wexer, W3, disc,
                                             exer_id, kn, bstu, bexer, b3, (float*)d_out);
}

// Round 15
// 178.332 us; speedup vs baseline: 1.3745x; 1.0004x over previous
//
#include <hip/hip_runtime.h>

#define NN 16512      // N = K + EXER nodes
#define KK 128        // feature dim
#define K3 384        // 3 graphs concatenated along K
#define EE 262144     // edges per graph
#define BB 2048       // batch
#define HH 64         // history length
#define NKf ((size_t)NN * KK)
#define NB 64         // hist blocks per graph
#define EPB (EE / NB) // 4096 edges per block
#define NP (NN / 2)   // 8256 packed u16-pair counters
#define RPB 16        // rows per k_layer block
#define CAP 512       // staged edges per graph per block (mean ~254)

typedef unsigned int u32;
typedef unsigned short u16;
typedef short bf16x8 __attribute__((ext_vector_type(8)));
typedef float f32x4 __attribute__((ext_vector_type(4)));

__device__ __forceinline__ float sgm(float x) { return 1.0f / (1.0f + __expf(-x)); }

__device__ __forceinline__ u16 f2bf(float f) {          // round-to-nearest-even
  u32 u = __float_as_uint(f);
  u32 r = u + 0x7fffu + ((u >> 16) & 1u);
  return (u16)(r >> 16);
}
__device__ __forceinline__ float bflo(u32 p) { return __uint_as_float(p << 16); }
__device__ __forceinline__ float bfhi(u32 p) { return __uint_as_float(p & 0xffff0000u); }

// ---------------- graph preprocessing (atomic-free counting sort) ----------------

__global__ __launch_bounds__(256) void k_hist(
    const int* __restrict__ s0, const int* __restrict__ d0,
    const int* __restrict__ s1, const int* __restrict__ d1,
    const int* __restrict__ s2, const int* __restrict__ d2,
    u32* __restrict__ slabO, u32* __restrict__ slabI) {
  int g = blockIdx.y, b = blockIdx.x;
  const int* src = g == 0 ? s0 : (g == 1 ? s1 : s2);
  const int* dst = g == 0 ? d0 : (g == 1 ? d1 : d2);
  __shared__ u32 hO[NP], hI[NP];
  for (int i = threadIdx.x; i < NP; i += 256) { hO[i] = 0; hI[i] = 0; }
  __syncthreads();
  int base = b * EPB;
  for (int i = threadIdx.x; i < EPB; i += 256) {
    int s = src[base + i], d = dst[base + i];
    atomicAdd(&hO[s >> 1], 1u << ((s & 1) * 16));
    atomicAdd(&hI[d >> 1], 1u << ((d & 1) * 16));
  }
  __syncthreads();
  u32* oO = slabO + ((size_t)g * NB + b) * NP;
  u32* oI = slabI + ((size_t)g * NB + b) * NP;
  for (int i = threadIdx.x; i < NP; i += 256) { oO[i] = hO[i]; oI[i] = hI[i]; }
}

__global__ void k_reduce(u32* __restrict__ slabO, u32* __restrict__ slabI,
                         u32* __restrict__ degI, float* __restrict__ rsdO,
                         float* __restrict__ rsdI) {
  int g = blockIdx.y;
  int t = blockIdx.x * 256 + threadIdx.x;
  if (t >= NP) return;
  u32* sO = slabO + (size_t)g * NB * NP + t;
  u32* sI = slabI + (size_t)g * NB * NP + t;
  u32 sumO = 0, pre = 0;
  #pragma unroll 8
  for (int b = 0; b < NB; ++b) sumO += sO[(size_t)b * NP];
  #pragma unroll 8
  for (int b = 0; b < NB; ++b) {
    u32 v = sI[(size_t)b * NP];
    sI[(size_t)b * NP] = pre;          // packed u16 exclusive prefix
    pre += v;
  }
  u32 dOl = sumO & 0xffffu, dOh = sumO >> 16;
  u32 dIl = pre & 0xffffu,  dIh = pre >> 16;
  *(uint2*)(degI + (size_t)g * NN + 2 * t) = make_uint2(dIl, dIh);
  *(float2*)(rsdO + (size_t)g * NN + 2 * t) =
      make_float2(rsqrtf((float)(dOl ? dOl : 1u)), rsqrtf((float)(dOh ? dOh : 1u)));
  *(float2*)(rsdI + (size_t)g * NN + 2 * t) =
      make_float2(rsqrtf((float)(dIl ? dIl : 1u)), rsqrtf((float)(dIh ? dIh : 1u)));
}

__global__ __launch_bounds__(1024) void k_exscan2(const u32* __restrict__ degI,
                                                  u32* __restrict__ rps) {
  int g = blockIdx.x;
  const u32* deg = degI + (size_t)g * NN;
  u32* rp = rps + (size_t)g * (NN + 1);
  int t = threadIdx.x;
  int i0 = t * 17, i1 = i0 + 17 < NN ? i0 + 17 : NN;
  u32 s = 0;
  for (int i = i0; i < i1; ++i) s += deg[i];
  u32 x = s;
  int lane = t & 63, wid = t >> 6;
  #pragma unroll
  for (int off = 1; off < 64; off <<= 1) {
    u32 y = __shfl_up(x, off);
    if (lane >= off) x += y;
  }
  __shared__ u32 wsums[16];
  if (lane == 63) wsums[wid] = x;
  __syncthreads();
  if (t == 0) {
    u32 run = 0;
    #pragma unroll
    for (int i = 0; i < 16; ++i) { u32 tmp = wsums[i]; wsums[i] = run; run += tmp; }
  }
  __syncthreads();
  u32 run = wsums[wid] + x - s;
  for (int i = i0; i < i1; ++i) { rp[i] = run; run += deg[i]; }
  if (t == 0) rp[NN] = EE;
}

// edata[idx] = { src, norm(f32) } -> single 8B store per edge
__global__ __launch_bounds__(256) void k_scatter2(
    const int* __restrict__ s0, const int* __restrict__ d0,
    const int* __restrict__ s1, const int* __restrict__ d1,
    const int* __restrict__ s2, const int* __restrict__ d2,
    const u32* __restrict__ slabI, const u32* __restrict__ rps,
    const float* __restrict__ rsdO, const float* __restrict__ rsdI,
    uint2* __restrict__ edatas) {
  int g = blockIdx.y, b = blockIdx.x;
  const int* src = g == 0 ? s0 : (g == 1 ? s1 : s2);
  const int* dst = g == 0 ? d0 : (g == 1 ? d1 : d2);
  const u32* rp = rps + (size_t)g * (NN + 1);
  const u32* pre = slabI + ((size_t)g * NB + b) * NP;
  const float* rO = rsdO + (size_t)g * NN;
  const float* rI = rsdI + (size_t)g * NN;
  uint2* ed = edatas + (size_t)g * EE;
  __shared__ u32 cur[NN];
  for (int i = threadIdx.x; i < NP; i += 256) {
    u32 p = pre[i];
    cur[2 * i]     = rp[2 * i] + (p & 0xffffu);
    cur[2 * i + 1] = rp[2 * i + 1] + (p >> 16);
  }
  __syncthreads();
  int base = b * EPB;
  for (int i = threadIdx.x; i < EPB; i += 256) {
    int s = src[base + i], d = dst[base + i];
    u32 idx = atomicAdd(&cur[d], 1u);
    ed[idx] = make_uint2((u32)s, __float_as_uint(rO[s] * rI[d]));
  }
}

// ---------------- fused prep: entity->bf16 | W pre-swizzle | bias sums ----------------
// Bsw[((l*96 + nb*12 + ks)*64 + lane)*8 + j] = bf16( W[l, g, kin, kout] )
//   k = ks*32 + (lane>>4)*8 + j ; g = k>>7 ; kin = k&127 ; kout = nb*16 + (lane&15)

__global__ void k_prep(const float* __restrict__ entity, u16* __restrict__ xent,
                       const float* __restrict__ W, u16* __restrict__ Bsw,
                       const float* __restrict__ b, float* __restrict__ bsum) {
  int bid = blockIdx.x;
  if (bid < 1032) {                       // cvt: NN*KK/8 = 264192 items
    int t = bid * 256 + threadIdx.x;
    if (t >= NN * KK / 8) return;
    const float4* p = (const float4*)entity + (size_t)t * 2;
    float4 v0 = p[0], v1 = p[1];
    bf16x8 o;
    o[0] = (short)f2bf(v0.x); o[1] = (short)f2bf(v0.y);
    o[2] = (short)f2bf(v0.z); o[3] = (short)f2bf(v0.w);
    o[4] = (short)f2bf(v1.x); o[5] = (short)f2bf(v1.y);
    o[6] = (short)f2bf(v1.z); o[7] = (short)f2bf(v1.w);
    *(bf16x8*)(xent + (size_t)t * 8) = o;
  } else if (bid < 1104) {                // prepB: 18432 items
    int t = (bid - 1032) * 256 + threadIdx.x;
    if (t >= 3 * 8 * 12 * 64) return;
    int lane = t & 63;
    int ks = (t >> 6) % 12;
    int nb = ((t >> 6) / 12) % 8;
    int l  = (t >> 6) / 96;
    int kout = nb * 16 + (lane & 15);
    int kb = ks * 32 + (lane >> 4) * 8;
    bf16x8 v;
    #pragma unroll
    for (int j = 0; j < 8; ++j) {
      int k = kb + j; int g = k >> 7; int kin = k & 127;
      v[j] = (short)f2bf(W[(((size_t)l * 3 + g) * KK + kin) * KK + kout]);
    }
    *(bf16x8*)(Bsw + (size_t)t * 8) = v;
  } else {                                // bias sums: 384 items
    int t = (bid - 1104) * 256 + threadIdx.x;
    if (t >= 3 * KK) return;
    int l = t >> 7, c = t & 127;
    bsum[l * KK + c] = b[(l * 3 + 0) * KK + c] + b[(l * 3 + 1) * KK + c] + b[(l * 3 + 2) * KK + c];
  }
}

// ---------------- fused layer: SpMM (3 graphs -> LDS) + MFMA GEMM + epilogue ----------
// r14 structure + LDS WORK-QUEUE: waves pull row-tasks dynamically (intra-block
// balance; block time ~= total/8 instead of max-wave). Output bit-identical.
// mode: 1 = Sx = entity + v ; else Sx += v
//       2 = Ss = v ; 4 = Ssb = bf16(Ss + v) ; 8 = skip h write

#define ACC8(P, N)                                                 \
  acc[0] += bflo(P.x) * N; acc[1] += bfhi(P.x) * N;                \
  acc[2] += bflo(P.y) * N; acc[3] += bfhi(P.y) * N;                \
  acc[4] += bflo(P.z) * N; acc[5] += bfhi(P.z) * N;                \
  acc[6] += bflo(P.w) * N; acc[7] += bfhi(P.w) * N;

#define GATHER_LOOP(MP)                                            \
  for (; e + 16 <= cnt; e += 16) {                                 \
    uint2 ma = MP[e + slot];                                       \
    uint2 mb = MP[e + 4 + slot];                                   \
    uint2 mc = MP[e + 8 + slot];                                   \
    uint2 md = MP[e + 12 + slot];                                  \
    uint4 pa = *(const uint4*)(x + (size_t)ma.x * KK + cg * 8);    \
    uint4 pb = *(const uint4*)(x + (size_t)mb.x * KK + cg * 8);    \
    uint4 pc = *(const uint4*)(x + (size_t)mc.x * KK + cg * 8);    \
    uint4 pd = *(const uint4*)(x + (size_t)md.x * KK + cg * 8);    \
    float na = __uint_as_float(ma.y), nb2 = __uint_as_float(mb.y); \
    float nc = __uint_as_float(mc.y), nd = __uint_as_float(md.y);  \
    ACC8(pa, na) ACC8(pb, nb2) ACC8(pc, nc) ACC8(pd, nd)           \
  }                                                                \
  for (; e + 4 <= cnt; e += 4) {                                   \
    uint2 m = MP[e + slot];                                        \
    float n = __uint_as_float(m.y);                                \
    uint4 p = *(const uint4*)(x + (size_t)m.x * KK + cg * 8);      \
    ACC8(p, n)                                                     \
  }                                                                \
  if (e + slot < cnt) {                                            \
    uint2 m = MP[e + slot];                                        \
    float n = __uint_as_float(m.y);                                \
    uint4 p = *(const uint4*)(x + (size_t)m.x * KK + cg * 8);      \
    ACC8(p, n)                                                     \
  }

__global__ __launch_bounds__(512) void k_layer(
    const u16* __restrict__ x, const u32* __restrict__ rps,
    const uint2* __restrict__ edatas, const u16* __restrict__ Bsw,
    const float* __restrict__ bsum, u16* __restrict__ hout,
    const float* __restrict__ entity, float* __restrict__ Sx,
    float* __restrict__ Ss, u16* __restrict__ Ssb, int mode)
{
  __shared__ u16 At[RPB][392];            // 12.25 KB; also reused as f32 scratch (8 KB)
  __shared__ uint2 meta[3][CAP];          // 12 KB staged edge metadata
  __shared__ u32 rpl[3][RPB + 1];         // row pointers
  __shared__ u32 qctr;                    // dynamic task counter
  const int tid = threadIdx.x;
  const int wv = tid >> 6, lane = tid & 63;
  const int m0 = blockIdx.x * RPB;
  const int slot = lane >> 4, cg = lane & 15;

  if (tid < 3 * (RPB + 1))
    rpl[tid / (RPB + 1)][tid % (RPB + 1)] =
        rps[(size_t)(tid / (RPB + 1)) * (NN + 1) + m0 + tid % (RPB + 1)];
  if (tid == 0) qctr = 8;                 // tasks 0..7 statically seeded
  __syncthreads();

  // ---- stage edge metadata (contiguous CSR slices) ----
  #pragma unroll
  for (int g = 0; g < 3; ++g) {
    u32 b0 = rpl[g][0];
    u32 cnt = rpl[g][RPB] - b0; if (cnt > CAP) cnt = CAP;
    const uint2* ed = edatas + (size_t)g * EE + b0;
    for (u32 i = tid; i < cnt; i += 512) meta[g][i] = ed[i];
  }
  __syncthreads();

  // ---- SpMM phase: 48 row-tasks pulled from LDS queue ----
  int t = wv;
  while (t < 48) {
    int g = t >> 4, r = t & 15;
    u32 beg = rpl[g][r], cnt = rpl[g][r + 1] - beg;
    float acc[8] = {0.f, 0.f, 0.f, 0.f, 0.f, 0.f, 0.f, 0.f};
    u32 e = 0;
    if (rpl[g][RPB] - rpl[g][0] <= CAP) {
      const uint2* mp = &meta[g][beg - rpl[g][0]];
      GATHER_LOOP(mp)
    } else {                              // overflow fallback (rare)
      const uint2* mp = edatas + (size_t)g * EE + beg;
      GATHER_LOOP(mp)
    }
    #pragma unroll
    for (int i = 0; i < 8; ++i) {
      acc[i] += __shfl_xor(acc[i], 16);
      acc[i] += __shfl_xor(acc[i], 32);
    }
    if (slot == 0) {
      u32 o0 = ((u32)f2bf(acc[1]) << 16) | (u32)f2bf(acc[0]);
      u32 o1 = ((u32)f2bf(acc[3]) << 16) | (u32)f2bf(acc[2]);
      u32 o2 = ((u32)f2bf(acc[5]) << 16) | (u32)f2bf(acc[4]);
      u32 o3 = ((u32)f2bf(acc[7]) << 16) | (u32)f2bf(acc[6]);
      *(uint4*)(&At[r][g * KK + cg * 8]) = make_uint4(o0, o1, o2, o3);
    }
    u32 nt;
    if (lane == 0) nt = atomicAdd(&qctr, 1u);
    nt = __shfl(nt, 0);
    t = (int)nt;
  }
  __syncthreads();

  // ---- MFMA phase: 16x128 = At(16x384) @ B(384x128); wave wv -> cols wv*16.. ----
  const int lr = lane & 15, lk = lane >> 4;
  f32x4 acc2 = {0.f, 0.f, 0.f, 0.f};
  const u16* aB = Bsw + (size_t)wv * 6144 + (size_t)lane * 8;
  #pragma unroll
  for (int ks = 0; ks < 12; ++ks) {
    bf16x8 a = *(const bf16x8*)(&At[lr][ks * 32 + lk * 8]);
    bf16x8 b = *(const bf16x8*)(aB + ks * 512);
    acc2 = __builtin_amdgcn_mfma_f32_16x16x32_bf16(a, b, acc2, 0, 0, 0);
  }
  __syncthreads();                        // all MFMA reads of At done

  // ---- transpose acc through LDS (At reused as 16x128 f32 = 8 KB) ----
  float* Af = (float*)&At[0][0];
  {
    int col = wv * 16 + lr;
    int rowb = lk * 4;
    #pragma unroll
    for (int r = 0; r < 4; ++r) Af[(rowb + r) * KK + col] = acc2[r];
  }
  __syncthreads();

  // ---- vectorized epilogue: thread t -> row t/32, cols (t%32)*4 (float4) ----
  {
    int row = tid >> 5, c4 = (tid & 31) * 4;
    size_t idx = (size_t)(m0 + row) * KK + c4;
    f32x4 v = *(f32x4*)&Af[row * KK + c4];
    f32x4 bv = *(const f32x4*)&bsum[c4];
    v[0] += bv[0]; v[1] += bv[1]; v[2] += bv[2]; v[3] += bv[3];
    if (!(mode & 8)) {
      u32 h0 = ((u32)f2bf(v[1]) << 16) | (u32)f2bf(v[0]);
      u32 h1 = ((u32)f2bf(v[3]) << 16) | (u32)f2bf(v[2]);
      *(uint2*)(hout + idx) = make_uint2(h0, h1);
    }
    f32x4 sx;
    if (mode & 1) {
      f32x4 ev = *(const f32x4*)(entity + idx);
      sx[0] = ev[0] + v[0]; sx[1] = ev[1] + v[1];
      sx[2] = ev[2] + v[2]; sx[3] = ev[3] + v[3];
    } else {
      f32x4 s = *(const f32x4*)(Sx + idx);
      sx[0] = s[0] + v[0]; sx[1] = s[1] + v[1];
      sx[2] = s[2] + v[2]; sx[3] = s[3] + v[3];
    }
    *(f32x4*)(Sx + idx) = sx;
    if (mode & 2) {
      *(f32x4*)(Ss + idx) = v;
    } else if (mode & 4) {
      f32x4 s = *(const f32x4*)(Ss + idx);
      u32 h0 = ((u32)f2bf(s[1] + v[1]) << 16) | (u32)f2bf(s[0] + v[0]);
      u32 h1 = ((u32)f2bf(s[3] + v[3]) << 16) | (u32)f2bf(s[2] + v[2]);
      *(uint2*)(Ssb + idx) = make_uint2(h0, h1);
    }
  }
}

// ---------------- fused post: history mean (quad rows) + concept projections ----------

__global__ __launch_bounds__(256) void k_post(
    const u16* __restrict__ Ssb, const int* __restrict__ hist, const int* __restrict__ hlen,
    float* __restrict__ semb, const float* __restrict__ Sx,
    const float* __restrict__ Wstu, const float* __restrict__ Wexer,
    float* __restrict__ cstu, float* __restrict__ cexer)
{
  int wv = threadIdx.x >> 6, lane = threadIdx.x & 63;
  if (blockIdx.x < 512) {                 // stuemb: 2048 items
    int item = blockIdx.x * 4 + wv;
    int slot = lane >> 4, cg = lane & 15;
    int len = hlen[item];
    const int* hrow = hist + item * HH;
    float acc[8] = {0.f, 0.f, 0.f, 0.f, 0.f, 0.f, 0.f, 0.f};
    int h = 0;
    for (; h + 4 <= len; h += 4) {
      int id = hrow[h + slot];
      uint4 p = *(const uint4*)(Ssb + (size_t)(KK + id) * KK + cg * 8);
      acc[0] += bflo(p.x); acc[1] += bfhi(p.x);
      acc[2] += bflo(p.y); acc[3] += bfhi(p.y);
      acc[4] += bflo(p.z); acc[5] += bfhi(p.z);
      acc[6] += bflo(p.w); acc[7] += bfhi(p.w);
    }
    if (h + slot < len) {
      int id = hrow[h + slot];
      uint4 p = *(const uint4*)(Ssb + (size_t)(KK + id) * KK + cg * 8);
      acc[0] += bflo(p.x); acc[1] += bfhi(p.x);
      acc[2] += bflo(p.y); acc[3] += bfhi(p.y);
      acc[4] += bflo(p.z); acc[5] += bfhi(p.z);
      acc[6] += bflo(p.w); acc[7] += bfhi(p.w);
    }
    #pragma unroll
    for (int i = 0; i < 8; ++i) {
      acc[i] += __shfl_xor(acc[i], 16);
      acc[i] += __shfl_xor(acc[i], 32);
    }
    if (slot == 0) {
      float sc = 0.5f / (float)len;
      float4 o0 = make_float4(acc[0] * sc, acc[1] * sc, acc[2] * sc, acc[3] * sc);
      float4 o1 = make_float4(acc[4] * sc, acc[5] * sc, acc[6] * sc, acc[7] * sc);
      *(float4*)(semb + (size_t)item * KK + cg * 8) = o0;
      *(float4*)(semb + (size_t)item * KK + cg * 8 + 4) = o1;
    }
  } else {                                // cproj: 128 concept rows
    int w = (blockIdx.x - 512) * 4 + wv;
    float2 c = *(const float2*)(Sx + (size_t)w * KK + lane * 2);
    c.x *= 0.25f; c.y *= 0.25f;
    float2 ws = *(const float2*)(Wstu + KK + lane * 2);
    float2 we = *(const float2*)(Wexer + KK + lane * 2);
    float ps = c.x * ws.x + c.y * ws.y;
    float pe = c.x * we.x + c.y * we.y;
    #pragma unroll
    for (int off = 32; off; off >>= 1) { ps += __shfl_xor(ps, off); pe += __shfl_xor(pe, off); }
    if (lane == 0) { cstu[w] = ps; cexer[w] = pe; }
  }
}

__global__ void k_final(const float* __restrict__ Sx, const float* __restrict__ semb,
                        const float* __restrict__ cstu, const float* __restrict__ cexer,
                        const float* __restrict__ Wstu, const float* __restrict__ Wexer,
                        const float* __restrict__ W3, const float* __restrict__ disc,
                        const int* __restrict__ exid, const float* __restrict__ kn,
                        const float* __restrict__ bstu, const float* __restrict__ bexer,
                        const float* __restrict__ b3, float* __restrict__ out) {
  int w = (blockIdx.x * 256 + threadIdx.x) >> 6;   // batch index
  int lane = threadIdx.x & 63;
  if (w >= BB) return;
  int eid = exid[w];
  float2 se = *(const float2*)(Sx + ((size_t)(KK + eid)) * KK + lane * 2);
  se.x *= 0.25f; se.y *= 0.25f;                    // exer_emb
  float2 sm = *(const float2*)(semb + (size_t)w * KK + lane * 2);
  float2 ws = *(const float2*)(Wstu + lane * 2);
  float2 we = *(const float2*)(Wexer + lane * 2);
  float ps = sm.x * ws.x + sm.y * ws.y;
  float pe = se.x * we.x + se.y * we.y;
  #pragma unroll
  for (int off = 32; off; off >>= 1) { ps += __shfl_xor(ps, off); pe += __shfl_xor(pe, off); }
  float s_stu = ps + bstu[0];
  float s_exer = pe + bexer[0];
  float ed = 10.f * sgm(disc[eid]);
  float2 cs = *(const float2*)(cstu + lane * 2);
  float2 ce = *(const float2*)(cexer + lane * 2);
  float2 knv = *(const float2*)(kn + (size_t)w * KK + lane * 2);
  float x0 = ed * (sgm(s_stu + cs.x) - sgm(s_exer + ce.x)) * knv.x;
  float x1 = ed * (sgm(s_stu + cs.y) - sgm(s_exer + ce.y)) * knv.y;
  float2 w3v = *(const float2*)(W3 + lane * 2);
  float px = x0 * w3v.x + x1 * w3v.y;
  #pragma unroll
  for (int off = 32; off; off >>= 1) px += __shfl_xor(px, off);
  if (lane == 0) out[w] = sgm(px + b3[0]);
}

// ---------------- host ----------------

extern "C" void kernel_launch(void* const* d_in, const int* in_sizes, int n_in,
                              void* d_out, int out_size, void* d_ws, size_t ws_size,
                              hipStream_t stream)
{
  const float* entity = (const float*)d_in[0];
  const float* gcnW   = (const float*)d_in[1];
  const float* gcnB   = (const float*)d_in[2];
  const float* disc   = (const float*)d_in[3];
  const float* Wstu   = (const float*)d_in[4];
  const float* bstu   = (const float*)d_in[5];
  const float* Wexer  = (const float*)d_in[6];
  const float* bexer  = (const float*)d_in[7];
  const float* W3     = (const float*)d_in[8];
  const float* b3     = (const float*)d_in[9];
  const float* kn     = (const float*)d_in[10];
  const int* exer_id  = (const int*)d_in[12];
  const int* history  = (const int*)d_in[14];
  const int* hlen     = (const int*)d_in[15];
  const int* s0 = (const int*)d_in[16], *dd0 = (const int*)d_in[17];
  const int* s1 = (const int*)d_in[18], *dd1 = (const int*)d_in[19];
  const int* s2 = (const int*)d_in[20], *dd2 = (const int*)d_in[21];

  char* ws = (char*)d_ws;
  size_t off = 0;
  auto take = [&](size_t bytes) -> char* {
    char* p = ws + off;
    off = (off + bytes + 255) & ~(size_t)255;
    return p;
  };
  u16*   xent  = (u16*)take(NKf * 2);
  u16*   hA    = (u16*)take(NKf * 2);
  u16*   hB    = (u16*)take(NKf * 2);
  float* Sx    = (float*)take(NKf * 4);
  float* Ss    = (float*)take(NKf * 4);
  u16*   Ssb   = (u16*)take(NKf * 2);
  float* semb  = (float*)take((size_t)BB * KK * 4);
  float* cstu  = (float*)take(KK * 4);
  float* cexer = (float*)take(KK * 4);
  u16*   Bsw   = (u16*)take((size_t)3 * 49152 * 2);
  float* bsum  = (float*)take((size_t)3 * KK * 4);
  u32*   degI  = (u32*)take((size_t)3 * NN * 4);
  float* rsdO  = (float*)take((size_t)3 * NN * 4);
  float* rsdI  = (float*)take((size_t)3 * NN * 4);
  u32*   rp    = (u32*)take((size_t)3 * (NN + 1) * 4);
  uint2* edata = (uint2*)take((size_t)3 * EE * 8);
  u32*   slabO = (u32*)take((size_t)3 * NB * NP * 4);
  u32*   slabI = (u32*)take((size_t)3 * NB * NP * 4);
  (void)ws_size; (void)in_sizes; (void)n_in; (void)out_size;

  k_hist<<<dim3(NB, 3), 256, 0, stream>>>(s0, dd0, s1, dd1, s2, dd2, slabO, slabI);
  k_reduce<<<dim3((NP + 255) / 256, 3), 256, 0, stream>>>(slabO, slabI, degI, rsdO, rsdI);
  k_exscan2<<<3, 1024, 0, stream>>>(degI, rp);
  k_scatter2<<<dim3(NB, 3), 256, 0, stream>>>(s0, dd0, s1, dd1, s2, dd2, slabI, rp,
                                              rsdO, rsdI, edata);
  k_prep<<<1106, 256, 0, stream>>>(entity, xent, gcnW, Bsw, gcnB, bsum);

  const u16* xs[3] = {xent, hA, hB};
  u16* outs[3]     = {hA, hB, hA};
  const int modes[3] = {1, 2, 4 | 8};
  for (int l = 0; l < 3; ++l)
    k_layer<<<NN / RPB, 512, 0, stream>>>(xs[l], rp, edata, Bsw + (size_t)l * 49152,
                                          bsum + (size_t)l * KK, outs[l], entity,
                                          Sx, Ss, Ssb, modes[l]);

  k_post<<<544, 256, 0, stream>>>(Ssb, history, hlen, semb, Sx, Wstu, Wexer, cstu, cexer);
  k_final<<<BB * 64 / 256, 256, 0, stream>>>(Sx, semb, cstu, cexer, Wstu, Wexer, W3, disc,
                                             exer_id, kn, bstu, bexer, b3, (float*)d_out);
}